// Round 1
// baseline (249.553 us; speedup 1.0000x reference)
//
#include <hip/hip_runtime.h>
#include <hip/hip_fp16.h>
#include <math.h>

// EnvironmentLight IBL shade, R11.
// R11 changes vs R10 (223 us):
//  1) envlight: 2 points/thread (512-pt blocks). Latency-bound fix: 8 independent
//     scattered uint4 loads in flight per wave (was 4), half the barriers/point.
//     s_in reused as out-staging (26.6KB LDS -> 6 blocks/CU = 24 waves, same occ).
//  2) repack: tiled. One block per 16x16-quad tile; encode the 17x17 texel
//     footprint ONCE into LDS (289 enc9e5 per 256 quads, was 1024), assemble
//     quads from LDS. Bitwise-identical quad buffer.

typedef unsigned int u32;

// ---------------- RGB9E5 ----------------
__device__ __forceinline__ u32 enc9e5(float r, float g, float b) {
    r = fminf(fmaxf(r, 0.f), 65408.f);
    g = fminf(fmaxf(g, 0.f), 65408.f);
    b = fminf(fmaxf(b, 0.f), 65408.f);
    float maxc = fmaxf(r, fmaxf(g, b));
    int e = ((__float_as_int(maxc) >> 23) & 0xff) - 127;
    int exp_p = max(e + 16, 0);
    float rd = __int_as_float((151 - exp_p) << 23);   // 2^(24-exp_p), exact
    int maxm = (int)(maxc * rd + 0.5f);
    if (maxm == 512) { exp_p += 1; rd *= 0.5f; }
    u32 rm = (u32)(r * rd + 0.5f);
    u32 gm = (u32)(g * rd + 0.5f);
    u32 bm = (u32)(b * rd + 0.5f);
    return rm | (gm << 9) | (bm << 18) | ((u32)exp_p << 27);
}

__device__ __forceinline__ void dec9e5_acc(u32 pk, float w, float& r, float& g, float& b) {
    float scale = __int_as_float((int)(((pk >> 27) & 31u) + 103u) << 23) * w;
    r += (float)(pk & 511u) * scale;
    g += (float)((pk >> 9) & 511u) * scale;
    b += (float)((pk >> 18) & 511u) * scale;
}

__device__ __forceinline__ void gather_q9(uint4 q, float tx, float ty,
                                          float& r, float& g, float& b) {
    float w00 = (1.f - tx) * (1.f - ty);
    float w01 = tx * (1.f - ty);
    float w10 = (1.f - tx) * ty;
    float w11 = tx * ty;
    r = 0.f; g = 0.f; b = 0.f;
    dec9e5_acc(q.x, w00, r, g, b);
    dec9e5_acc(q.y, w01, r, g, b);
    dec9e5_acc(q.z, w10, r, g, b);
    dec9e5_acc(q.w, w11, r, g, b);
}

__device__ __forceinline__ float srgb1(float x) {
    float p = 1.055f * __builtin_amdgcn_exp2f(
                  __builtin_amdgcn_logf(fmaxf(x, 0.0031308f)) * (1.0f / 2.4f)) - 0.055f;
    return (x <= 0.0031308f) ? (12.92f * x) : p;
}

__device__ __forceinline__ void cube_face_uv(float dx, float dy, float dz,
                                             int& face, float& u, float& v) {
    float ax = fabsf(dx), ay = fabsf(dy), az = fabsf(dz);
    bool is_x = (ax >= ay) && (ax >= az);
    bool is_y = (!is_x) && (ay >= az);
    face = is_x ? (dx > 0.f ? 0 : 1)
                : (is_y ? (dy > 0.f ? 2 : 3) : (dz > 0.f ? 4 : 5));
    float ma = fmaxf(is_x ? ax : (is_y ? ay : az), 1e-20f);
    float uu = is_x ? (dx > 0.f ? -dz : dz) : (is_y ? dx : (dz > 0.f ? dx : -dx));
    float vv = is_y ? (dy > 0.f ? dz : -dz) : -dy;
    float inv = __builtin_amdgcn_rcpf(ma);
    u = uu * inv;
    v = vv * inv;
}

// ---------------- layout constants ----------------
#define SPEC_TOTAL 2096640
#define DIF_OFF    SPEC_TOTAL
#define LUT_OFF    (SPEC_TOTAL + 1536)
#define ALL_QUADS  (SPEC_TOTAL + 1536 + 65536)
#define N_TILES    8452   // 8190 spec + 6 dif + 256 lut

// ---------------- tiled repack ----------------
// One block per 16x16-quad tile. Encode 17x17 clamped texel footprint once
// into LDS, assemble quads from LDS. Output bitwise-identical to R10 repack.
__global__ __launch_bounds__(256)
void repack_tiled(const float* __restrict__ s0, const float* __restrict__ s1,
                  const float* __restrict__ s2, const float* __restrict__ s3,
                  const float* __restrict__ s4, const float* __restrict__ s5,
                  const float* __restrict__ diffuse_map,
                  const float2* __restrict__ lut,
                  uint4* __restrict__ dst)
{
    __shared__ u32 L[289];
    int b = blockIdx.x;
    int tid = threadIdx.x;

    if (b >= 8196) {
        // ---- LUT tiles: 256x256 half2-packed ----
        int t = b - 8196;
        int ty0 = (t >> 4) << 4;
        int tx0 = (t & 15) << 4;
        for (int e = tid; e < 289; e += 256) {
            int ey = e / 17, ex = e - ey * 17;
            int gy = min(ty0 + ey, 255), gx = min(tx0 + ex, 255);
            float2 c = lut[(gy << 8) + gx];
            __half2 h = __floats2half2_rn(c.x, c.y);
            L[e] = *reinterpret_cast<u32*>(&h);
        }
        __syncthreads();
        int qx = tid & 15, qy = tid >> 4;
        uint4 qv;
        qv.x = L[qy * 17 + qx];       qv.y = L[qy * 17 + qx + 1];
        qv.z = L[(qy + 1) * 17 + qx]; qv.w = L[(qy + 1) * 17 + qx + 1];
        dst[LUT_OFF + ((ty0 + qy) << 8) + tx0 + qx] = qv;
        return;
    }

    // ---- spec/diffuse tiles ----
    const float* src; int lr, tbase, doff;
    if      (b < 6144) { src = s0; lr = 9; tbase = 0;    doff = 0; }
    else if (b < 7680) { src = s1; lr = 8; tbase = 6144; doff = 1572864; }
    else if (b < 8064) { src = s2; lr = 7; tbase = 7680; doff = 1966080; }
    else if (b < 8160) { src = s3; lr = 6; tbase = 8064; doff = 2064384; }
    else if (b < 8184) { src = s4; lr = 5; tbase = 8160; doff = 2088960; }
    else if (b < 8190) { src = s5; lr = 4; tbase = 8184; doff = 2095104; }
    else               { src = diffuse_map; lr = 4; tbase = 8190; doff = DIF_OFF; }

    int W = 1 << lr;
    int lt = lr - 4;                      // log2(tiles per dim)
    int local = b - tbase;
    int face = local >> (2 * lt);
    int rem  = local & ((1 << (2 * lt)) - 1);
    int ty0 = (rem >> lt) << 4;
    int tx0 = (rem & ((1 << lt) - 1)) << 4;
    int fbase = face << (2 * lr);

    for (int e = tid; e < 289; e += 256) {
        int ey = e / 17, ex = e - ey * 17;
        int gy = min(ty0 + ey, W - 1), gx = min(tx0 + ex, W - 1);
        int idx = 3 * (fbase + (gy << lr) + gx);
        L[e] = enc9e5(src[idx], src[idx + 1], src[idx + 2]);
    }
    __syncthreads();
    int qx = tid & 15, qy = tid >> 4;
    uint4 qv;
    qv.x = L[qy * 17 + qx];       qv.y = L[qy * 17 + qx + 1];
    qv.z = L[(qy + 1) * 17 + qx]; qv.w = L[(qy + 1) * 17 + qx + 1];
    dst[doff + fbase + ((ty0 + qy) << lr) + tx0 + qx] = qv;
}

// ---------------- main kernel: 2 points/thread, LDS-staged I/O ----------------
// s_in float layout (512 pts): vd[0..1535] nm[1536..3071] kd[3072..4607]
//   ks[4608..6143] occ[6144..6655]  = 6656 floats = 26624 B.
// Out staging reuses s_in[0..1535] after a barrier.

struct PtA {
    float kdx, kdy, kdz, ks0, met, occ;
    float dtx, dty, ltx, lty, atx, aty, btx, bty, fmip;
    int aI, bI, lI, dI;     // absolute quad indices
};

__device__ __forceinline__ void prep_pt(const float* s, int t, PtA& p) {
    float vx = s[3 * t],        vy = s[3 * t + 1],        vz = s[3 * t + 2];
    float nx = s[1536 + 3 * t], ny = s[1536 + 3 * t + 1], nz = s[1536 + 3 * t + 2];
    p.kdx = s[3072 + 3 * t]; p.kdy = s[3072 + 3 * t + 1]; p.kdz = s[3072 + 3 * t + 2];
    p.ks0 = s[4608 + 3 * t];
    float rough = s[4608 + 3 * t + 1];
    p.met = s[4608 + 3 * t + 2];
    p.occ = s[6144 + t];

    // reflect + normalize
    float vdotn = vx * nx + vy * ny + vz * nz;
    float rx = 2.f * vdotn * nx - vx;
    float ry = 2.f * vdotn * ny - vy;
    float rz = 2.f * vdotn * nz - vz;
    float rinv = __builtin_amdgcn_rsqf(fmaxf(rx * rx + ry * ry + rz * rz, 1e-20f));
    rx *= rinv; ry *= rinv; rz *= rinv;

    // diffuse address (lr=4)
    {
        int face; float u, v;
        cube_face_uv(nx, ny, nz, face, u, v);
        float fx = (u * 0.5f + 0.5f) * 16.f - 0.5f;
        float fy = (v * 0.5f + 0.5f) * 16.f - 0.5f;
        float x0f = floorf(fx), y0f = floorf(fy);
        p.dtx = fx - x0f; p.dty = fy - y0f;
        int x0 = min(max((int)x0f, 0), 15);
        int y0 = min(max((int)y0f, 0), 15);
        p.dI = DIF_OFF + (face << 8) + (y0 << 4) + x0;
    }

    // LUT address
    {
        float NdotV = fmaxf(vdotn, 1e-4f);
        float fx = NdotV * 256.f - 0.5f;
        float fy = rough * 256.f - 0.5f;
        float x0f = floorf(fx), y0f = floorf(fy);
        p.ltx = fx - x0f; p.lty = fy - y0f;
        int x0 = min(max((int)x0f, 0), 255);
        int y0 = min(max((int)y0f, 0), 255);
        p.lI = LUT_OFF + (y0 << 8) + x0;
    }

    // mip selection
    const float MINR = 0.08f, MAXR = 0.5f;
    float lo = (fminf(fmaxf(rough, MINR), MAXR) - MINR) * (4.0f / (MAXR - MINR));
    float hi = (fminf(fmaxf(rough, MAXR), 1.0f) - MAXR) * (1.0f / (1.0f - MAXR)) + 4.0f;
    float lvl = fminf(fmaxf((rough < MAXR) ? lo : hi, 0.f), 5.f);
    int l0 = min(max((int)floorf(lvl), 0), 5);
    int l1 = min(l0 + 1, 5);
    p.fmip = lvl - (float)l0;

    // spec A address; B derived (same face, half-res coords)
    {
        int face; float u, v;
        cube_face_uv(rx, ry, rz, face, u, v);
        int lrA = 9 - l0, lrB = 9 - l1;
        float RA = (float)(1 << lrA);
        float fxA = (u * 0.5f + 0.5f) * RA - 0.5f;
        float fyA = (v * 0.5f + 0.5f) * RA - 0.5f;
        float fxB = (l0 == l1) ? fxA : (fxA + 0.5f) * 0.5f - 0.5f;
        float fyB = (l0 == l1) ? fyA : (fyA + 0.5f) * 0.5f - 0.5f;

        float x0fA = floorf(fxA), y0fA = floorf(fyA);
        p.atx = fxA - x0fA; p.aty = fyA - y0fA;
        int WA = 1 << lrA;
        int x0A = min(max((int)x0fA, 0), WA - 1);
        int y0A = min(max((int)y0fA, 0), WA - 1);
        int aIdx = (face << (2 * lrA)) + (y0A << lrA) + x0A;

        float x0fB = floorf(fxB), y0fB = floorf(fyB);
        p.btx = fxB - x0fB; p.bty = fyB - y0fB;
        int WB = 1 << lrB;
        int x0B = min(max((int)x0fB, 0), WB - 1);
        int y0B = min(max((int)y0fB, 0), WB - 1);
        int bIdx = (face << (2 * lrB)) + (y0B << lrB) + x0B;

        static const int OFF[6] = {0, 1572864, 1966080, 2064384, 2088960, 2095104};
        p.aI = OFF[l0] + aIdx;
        p.bI = OFF[l1] + bIdx;
    }
}

__device__ __forceinline__ void finish_pt(const PtA& p, uint4 qA, uint4 qB,
                                          uint4 lq, uint4 dq, float* o) {
    float ar, ag, ab_, br, bg, bb;
    gather_q9(qA, p.atx, p.aty, ar, ag, ab_);
    gather_q9(qB, p.btx, p.bty, br, bg, bb);

    __half2 h00 = *reinterpret_cast<__half2*>(&lq.x);
    __half2 h01 = *reinterpret_cast<__half2*>(&lq.y);
    __half2 h10 = *reinterpret_cast<__half2*>(&lq.z);
    __half2 h11 = *reinterpret_cast<__half2*>(&lq.w);
    float2 c00 = __half22float2(h00), c01 = __half22float2(h01);
    float2 c10 = __half22float2(h10), c11 = __half22float2(h11);
    float lw00 = (1.f - p.ltx) * (1.f - p.lty);
    float lw01 = p.ltx * (1.f - p.lty);
    float lw10 = (1.f - p.ltx) * p.lty;
    float lw11 = p.ltx * p.lty;
    float fg0 = c00.x * lw00 + c01.x * lw01 + c10.x * lw10 + c11.x * lw11;
    float fg1 = c00.y * lw00 + c01.y * lw01 + c10.y * lw10 + c11.y * lw11;

    float dfr, dfg, dfb;
    gather_q9(dq, p.dtx, p.dty, dfr, dfg, dfb);
    dfr = fmaxf(dfr, 0.f); dfg = fmaxf(dfg, 0.f); dfb = fmaxf(dfb, 0.f);

    float spr = fmaxf(ar * (1.f - p.fmip) + br * p.fmip, 0.f);
    float spg = fmaxf(ag * (1.f - p.fmip) + bg * p.fmip, 0.f);
    float spb = fmaxf(ab_ * (1.f - p.fmip) + bb * p.fmip, 0.f);

    float m = p.met;
    float scx = (1.f - m) * 0.04f + p.kdx * m;
    float scy = (1.f - m) * 0.04f + p.kdy * m;
    float scz = (1.f - m) * 0.04f + p.kdz * m;
    float dcx = p.kdx * (1.f - m);
    float dcy = p.kdy * (1.f - m);
    float dcz = p.kdz * (1.f - m);

    float kds = 1.f - p.ks0;
    float om = 1.f - p.occ;
    float shx = dfr * dcx * kds + spr * (scx * fg0 + fg1) * om;
    float shy = dfg * dcy * kds + spg * (scy * fg0 + fg1) * om;
    float shz = dfb * dcz * kds + spb * (scz * fg0 + fg1) * om;

    o[0] = srgb1(fminf(fmaxf(shx, 0.f), 1.f));
    o[1] = srgb1(fminf(fmaxf(shy, 0.f), 1.f));
    o[2] = srgb1(fminf(fmaxf(shz, 0.f), 1.f));
}

__global__ __launch_bounds__(256, 6)
void envlight_lds2(const float* __restrict__ view_dir,
                   const float* __restrict__ normal,
                   const float* __restrict__ kd,
                   const float* __restrict__ ks,
                   const float* __restrict__ reflect_occ,
                   const uint4* __restrict__ q,
                   float* __restrict__ out, int n)
{
    __shared__ float s_in[6656];
    int tid = threadIdx.x;
    int base = blockIdx.x << 9;
    int nblk = min(512, n - base);

    if (nblk == 512) {
        const float4* v4 = (const float4*)(view_dir + 3 * base);
        const float4* n4 = (const float4*)(normal + 3 * base);
        const float4* k4 = (const float4*)(kd + 3 * base);
        const float4* q4 = (const float4*)(ks + 3 * base);
        const float4* o4 = (const float4*)(reflect_occ + base);
        float4* dst4 = (float4*)s_in;
        #pragma unroll
        for (int k = 0; k < 7; ++k) {
            int j = tid + (k << 8);
            if (j < 1664) {
                const float4* src; int off;
                if (j < 384)       { src = v4; off = j; }
                else if (j < 768)  { src = n4; off = j - 384; }
                else if (j < 1152) { src = k4; off = j - 768; }
                else if (j < 1536) { src = q4; off = j - 1152; }
                else               { src = o4; off = j - 1536; }
                dst4[j] = src[off];
            }
        }
    } else {
        for (int j = tid; j < nblk * 3; j += 256) {
            s_in[j]        = view_dir[3 * base + j];
            s_in[1536 + j] = normal[3 * base + j];
            s_in[3072 + j] = kd[3 * base + j];
            s_in[4608 + j] = ks[3 * base + j];
        }
        for (int j = tid; j < nblk; j += 256)
            s_in[6144 + j] = reflect_occ[base + j];
    }
    __syncthreads();

    bool a0 = (tid < nblk);
    bool a1 = (tid + 256 < nblk);

    PtA p0, p1;
    uint4 qA0, qB0, ql0, qd0, qA1, qB1, ql1, qd1;
    float o0[3], o1[3];

    if (a0) {
        prep_pt(s_in, tid, p0);
        qA0 = q[p0.aI]; qB0 = q[p0.bI]; ql0 = q[p0.lI]; qd0 = q[p0.dI];
    }
    if (a1) {
        prep_pt(s_in, tid + 256, p1);
        qA1 = q[p1.aI]; qB1 = q[p1.bI]; ql1 = q[p1.lI]; qd1 = q[p1.dI];
    }
    if (a0) finish_pt(p0, qA0, qB0, ql0, qd0, o0);
    if (a1) finish_pt(p1, qA1, qB1, ql1, qd1, o1);

    __syncthreads();   // all s_in reads done; reuse as out staging

    if (a0) {
        s_in[3 * tid + 0] = o0[0];
        s_in[3 * tid + 1] = o0[1];
        s_in[3 * tid + 2] = o0[2];
    }
    if (a1) {
        s_in[3 * (tid + 256) + 0] = o1[0];
        s_in[3 * (tid + 256) + 1] = o1[1];
        s_in[3 * (tid + 256) + 2] = o1[2];
    }
    __syncthreads();

    if (nblk == 512) {
        float4* ot4 = (float4*)(out + 3 * base);
        #pragma unroll
        for (int k = 0; k < 2; ++k) {
            int j = tid + (k << 8);
            if (j < 384) ot4[j] = ((const float4*)s_in)[j];
        }
    } else {
        for (int j = tid; j < nblk * 3; j += 256)
            out[3 * base + j] = s_in[j];
    }
}

// ---------------- raw-float fallback (ws too small; shouldn't trigger) ----------------
__global__ __launch_bounds__(256)
void envlight_raw(const float* __restrict__ view_dir,
                  const float* __restrict__ normal,
                  const float* __restrict__ kd,
                  const float* __restrict__ ks,
                  const float* __restrict__ reflect_occ,
                  const float* __restrict__ diffuse_map,
                  const float* __restrict__ s0, const float* __restrict__ s1,
                  const float* __restrict__ s2, const float* __restrict__ s3,
                  const float* __restrict__ s4, const float* __restrict__ s5,
                  const float* __restrict__ fg_lut,
                  float* __restrict__ out, int n)
{
    int i = blockIdx.x * blockDim.x + threadIdx.x;
    if (i >= n) return;

    float vx = view_dir[3 * i], vy = view_dir[3 * i + 1], vz = view_dir[3 * i + 2];
    float nx = normal[3 * i],  ny = normal[3 * i + 1],  nz = normal[3 * i + 2];
    float kdx = kd[3 * i], kdy = kd[3 * i + 1], kdz = kd[3 * i + 2];
    float ks0 = ks[3 * i], rough = ks[3 * i + 1], metallic = ks[3 * i + 2];
    float occ = reflect_occ[i];

    float vdotn = vx * nx + vy * ny + vz * nz;
    float rx = 2.f * vdotn * nx - vx;
    float ry = 2.f * vdotn * ny - vy;
    float rz = 2.f * vdotn * nz - vz;
    float rinv = __builtin_amdgcn_rsqf(fmaxf(rx * rx + ry * ry + rz * rz, 1e-20f));
    rx *= rinv; ry *= rinv; rz *= rinv;

    const float* mips[6] = {s0, s1, s2, s3, s4, s5};

    const float MINR = 0.08f, MAXR = 0.5f;
    float lo = (fminf(fmaxf(rough, MINR), MAXR) - MINR) * (4.0f / (MAXR - MINR));
    float hi = (fminf(fmaxf(rough, MAXR), 1.0f) - MAXR) * (1.0f / (1.0f - MAXR)) + 4.0f;
    float lvl = fminf(fmaxf((rough < MAXR) ? lo : hi, 0.f), 5.f);
    int l0 = min(max((int)floorf(lvl), 0), 5);
    int l1 = min(l0 + 1, 5);
    float f = lvl - (float)l0;

    float acc[3][3];
    float dirs[3][3] = {{nx, ny, nz}, {rx, ry, rz}, {rx, ry, rz}};
    int lrs[3] = {4, 9 - l0, 9 - l1};
    const float* texs[3] = {diffuse_map, mips[l0], mips[l1]};
    for (int s = 0; s < 3; ++s) {
        int face; float u, v;
        cube_face_uv(dirs[s][0], dirs[s][1], dirs[s][2], face, u, v);
        int lr = lrs[s], W = 1 << lr;
        float fx = (u * 0.5f + 0.5f) * (float)W - 0.5f;
        float fy = (v * 0.5f + 0.5f) * (float)W - 0.5f;
        float x0f = floorf(fx), y0f = floorf(fy);
        float tx = fx - x0f, ty = fy - y0f;
        int x0 = min(max((int)x0f, 0), W - 1);
        int x1 = min(x0 + 1, W - 1);
        int y0 = min(max((int)y0f, 0), W - 1);
        int y1 = min(y0 + 1, W - 1);
        int base = face << (2 * lr);
        const float* t = texs[s];
        const float* p00 = t + 3 * (base + (y0 << lr) + x0);
        const float* p01 = t + 3 * (base + (y0 << lr) + x1);
        const float* p10 = t + 3 * (base + (y1 << lr) + x0);
        const float* p11 = t + 3 * (base + (y1 << lr) + x1);
        float w00 = (1.f - tx) * (1.f - ty), w01 = tx * (1.f - ty);
        float w10 = (1.f - tx) * ty, w11 = tx * ty;
        for (int c = 0; c < 3; ++c)
            acc[s][c] = p00[c] * w00 + p01[c] * w01 + p10[c] * w10 + p11[c] * w11;
    }

    float NdotV = fmaxf(vdotn, 1e-4f);
    float fx = NdotV * 256.f - 0.5f, fy = rough * 256.f - 0.5f;
    float x0f = floorf(fx), y0f = floorf(fy);
    float tx = fx - x0f, ty = fy - y0f;
    int x0 = min(max((int)x0f, 0), 255);
    int x1 = min(x0 + 1, 255);
    int y0 = min(max((int)y0f, 0), 255);
    int y1 = min(y0 + 1, 255);
    const float2* lut2 = (const float2*)fg_lut;
    float2 c00 = lut2[(y0 << 8) + x0], c01 = lut2[(y0 << 8) + x1];
    float2 c10 = lut2[(y1 << 8) + x0], c11 = lut2[(y1 << 8) + x1];
    float w00 = (1.f - tx) * (1.f - ty), w01 = tx * (1.f - ty);
    float w10 = (1.f - tx) * ty, w11 = tx * ty;
    float fg0 = c00.x * w00 + c01.x * w01 + c10.x * w10 + c11.x * w11;
    float fg1 = c00.y * w00 + c01.y * w01 + c10.y * w10 + c11.y * w11;

    float dfr = fmaxf(acc[0][0], 0.f), dfg = fmaxf(acc[0][1], 0.f), dfb = fmaxf(acc[0][2], 0.f);
    float spr = fmaxf(acc[1][0] * (1.f - f) + acc[2][0] * f, 0.f);
    float spg = fmaxf(acc[1][1] * (1.f - f) + acc[2][1] * f, 0.f);
    float spb = fmaxf(acc[1][2] * (1.f - f) + acc[2][2] * f, 0.f);

    float m = metallic;
    float scx = (1.f - m) * 0.04f + kdx * m;
    float scy = (1.f - m) * 0.04f + kdy * m;
    float scz = (1.f - m) * 0.04f + kdz * m;
    float kds = 1.f - ks0;
    float om = 1.f - occ;
    float shx = dfr * kdx * (1.f - m) * kds + spr * (scx * fg0 + fg1) * om;
    float shy = dfg * kdy * (1.f - m) * kds + spg * (scy * fg0 + fg1) * om;
    float shz = dfb * kdz * (1.f - m) * kds + spb * (scz * fg0 + fg1) * om;

    out[3 * i + 0] = srgb1(fminf(fmaxf(shx, 0.f), 1.f));
    out[3 * i + 1] = srgb1(fminf(fmaxf(shy, 0.f), 1.f));
    out[3 * i + 2] = srgb1(fminf(fmaxf(shz, 0.f), 1.f));
}

extern "C" void kernel_launch(void* const* d_in, const int* in_sizes, int n_in,
                              void* d_out, int out_size, void* d_ws, size_t ws_size,
                              hipStream_t stream) {
    const float* view_dir    = (const float*)d_in[0];
    const float* normal      = (const float*)d_in[1];
    const float* kd          = (const float*)d_in[2];
    const float* ks          = (const float*)d_in[3];
    const float* reflect_occ = (const float*)d_in[4];
    const float* diffuse_map = (const float*)d_in[5];
    const float* s0          = (const float*)d_in[6];
    const float* s1          = (const float*)d_in[7];
    const float* s2          = (const float*)d_in[8];
    const float* s3          = (const float*)d_in[9];
    const float* s4          = (const float*)d_in[10];
    const float* s5          = (const float*)d_in[11];
    const float* fg_lut      = (const float*)d_in[12];
    float* out = (float*)d_out;

    int n = in_sizes[0] / 3;
    const size_t NEED_Q = (size_t)ALL_QUADS * 16;   // ~34.6 MB

    if (ws_size >= NEED_Q) {
        uint4* q = (uint4*)d_ws;
        repack_tiled<<<N_TILES, 256, 0, stream>>>(
            s0, s1, s2, s3, s4, s5, diffuse_map, (const float2*)fg_lut, q);
        int grid = (n + 511) / 512;
        envlight_lds2<<<grid, 256, 0, stream>>>(
            view_dir, normal, kd, ks, reflect_occ, q, out, n);
    } else {
        int grid = (n + 255) / 256;
        envlight_raw<<<grid, 256, 0, stream>>>(
            view_dir, normal, kd, ks, reflect_occ, diffuse_map,
            s0, s1, s2, s3, s4, s5, fg_lut, out, n);
    }
}

// Round 3
// 242.124 us; speedup vs baseline: 1.0307x; 1.0307x over previous
//
#include <hip/hip_runtime.h>
#include <hip/hip_fp16.h>
#include <math.h>

// EnvironmentLight IBL shade, R12 (resubmit — R2 bench was GPUAcquisitionTimeout,
// kernel never ran; no counters to act on).
// R11 post-mortem: 2-pt/thread pipeline spilled (WRITE_SIZE 24.6->102 MB = scratch).
// R12 keeps the 2-pt pipeline but cuts live-across-wait state below the
// launch_bounds(256,6) budget (~85 VGPR):
//  - finish-only inputs (kd/ks0/met/occ) re-read from LDS at finish, not carried
//  - OFF[] divergent-indexed array -> closed-form shift: OFF(l)=2^21-(2^21>>2l)
//  - outputs written into s_in's vd region (self-only access -> no extra barrier)
// Live state/pt across the texture wait: 9 fracs + 16 quad-dest regs = 25.
// repack_tiled unchanged from R11 (verified bitwise-equivalent, absmax same).

typedef unsigned int u32;

// ---------------- RGB9E5 ----------------
__device__ __forceinline__ u32 enc9e5(float r, float g, float b) {
    r = fminf(fmaxf(r, 0.f), 65408.f);
    g = fminf(fmaxf(g, 0.f), 65408.f);
    b = fminf(fmaxf(b, 0.f), 65408.f);
    float maxc = fmaxf(r, fmaxf(g, b));
    int e = ((__float_as_int(maxc) >> 23) & 0xff) - 127;
    int exp_p = max(e + 16, 0);
    float rd = __int_as_float((151 - exp_p) << 23);   // 2^(24-exp_p), exact
    int maxm = (int)(maxc * rd + 0.5f);
    if (maxm == 512) { exp_p += 1; rd *= 0.5f; }
    u32 rm = (u32)(r * rd + 0.5f);
    u32 gm = (u32)(g * rd + 0.5f);
    u32 bm = (u32)(b * rd + 0.5f);
    return rm | (gm << 9) | (bm << 18) | ((u32)exp_p << 27);
}

__device__ __forceinline__ void dec9e5_acc(u32 pk, float w, float& r, float& g, float& b) {
    float scale = __int_as_float((int)(((pk >> 27) & 31u) + 103u) << 23) * w;
    r += (float)(pk & 511u) * scale;
    g += (float)((pk >> 9) & 511u) * scale;
    b += (float)((pk >> 18) & 511u) * scale;
}

__device__ __forceinline__ void gather_q9(uint4 q, float tx, float ty,
                                          float& r, float& g, float& b) {
    float w00 = (1.f - tx) * (1.f - ty);
    float w01 = tx * (1.f - ty);
    float w10 = (1.f - tx) * ty;
    float w11 = tx * ty;
    r = 0.f; g = 0.f; b = 0.f;
    dec9e5_acc(q.x, w00, r, g, b);
    dec9e5_acc(q.y, w01, r, g, b);
    dec9e5_acc(q.z, w10, r, g, b);
    dec9e5_acc(q.w, w11, r, g, b);
}

__device__ __forceinline__ float srgb1(float x) {
    float p = 1.055f * __builtin_amdgcn_exp2f(
                  __builtin_amdgcn_logf(fmaxf(x, 0.0031308f)) * (1.0f / 2.4f)) - 0.055f;
    return (x <= 0.0031308f) ? (12.92f * x) : p;
}

__device__ __forceinline__ void cube_face_uv(float dx, float dy, float dz,
                                             int& face, float& u, float& v) {
    float ax = fabsf(dx), ay = fabsf(dy), az = fabsf(dz);
    bool is_x = (ax >= ay) && (ax >= az);
    bool is_y = (!is_x) && (ay >= az);
    face = is_x ? (dx > 0.f ? 0 : 1)
                : (is_y ? (dy > 0.f ? 2 : 3) : (dz > 0.f ? 4 : 5));
    float ma = fmaxf(is_x ? ax : (is_y ? ay : az), 1e-20f);
    float uu = is_x ? (dx > 0.f ? -dz : dz) : (is_y ? dx : (dz > 0.f ? dx : -dx));
    float vv = is_y ? (dy > 0.f ? dz : -dz) : -dy;
    float inv = __builtin_amdgcn_rcpf(ma);
    u = uu * inv;
    v = vv * inv;
}

// ---------------- layout constants ----------------
#define SPEC_TOTAL 2096640
#define DIF_OFF    SPEC_TOTAL
#define LUT_OFF    (SPEC_TOTAL + 1536)
#define ALL_QUADS  (SPEC_TOTAL + 1536 + 65536)
#define N_TILES    8452   // 8190 spec + 6 dif + 256 lut

// OFF(l) = 2^21 - (2^21 >> 2l): 0,1572864,1966080,2064384,2088960,2095104
__device__ __forceinline__ int spec_off(int l) {
    return (1 << 21) - ((1 << 21) >> (2 * l));
}

// ---------------- tiled repack (unchanged from R11, verified) ----------------
__global__ __launch_bounds__(256)
void repack_tiled(const float* __restrict__ s0, const float* __restrict__ s1,
                  const float* __restrict__ s2, const float* __restrict__ s3,
                  const float* __restrict__ s4, const float* __restrict__ s5,
                  const float* __restrict__ diffuse_map,
                  const float2* __restrict__ lut,
                  uint4* __restrict__ dst)
{
    __shared__ u32 L[289];
    int b = blockIdx.x;
    int tid = threadIdx.x;

    if (b >= 8196) {
        int t = b - 8196;
        int ty0 = (t >> 4) << 4;
        int tx0 = (t & 15) << 4;
        for (int e = tid; e < 289; e += 256) {
            int ey = e / 17, ex = e - ey * 17;
            int gy = min(ty0 + ey, 255), gx = min(tx0 + ex, 255);
            float2 c = lut[(gy << 8) + gx];
            __half2 h = __floats2half2_rn(c.x, c.y);
            L[e] = *reinterpret_cast<u32*>(&h);
        }
        __syncthreads();
        int qx = tid & 15, qy = tid >> 4;
        uint4 qv;
        qv.x = L[qy * 17 + qx];       qv.y = L[qy * 17 + qx + 1];
        qv.z = L[(qy + 1) * 17 + qx]; qv.w = L[(qy + 1) * 17 + qx + 1];
        dst[LUT_OFF + ((ty0 + qy) << 8) + tx0 + qx] = qv;
        return;
    }

    const float* src; int lr, tbase, doff;
    if      (b < 6144) { src = s0; lr = 9; tbase = 0;    doff = 0; }
    else if (b < 7680) { src = s1; lr = 8; tbase = 6144; doff = 1572864; }
    else if (b < 8064) { src = s2; lr = 7; tbase = 7680; doff = 1966080; }
    else if (b < 8160) { src = s3; lr = 6; tbase = 8064; doff = 2064384; }
    else if (b < 8184) { src = s4; lr = 5; tbase = 8160; doff = 2088960; }
    else if (b < 8190) { src = s5; lr = 4; tbase = 8184; doff = 2095104; }
    else               { src = diffuse_map; lr = 4; tbase = 8190; doff = DIF_OFF; }

    int W = 1 << lr;
    int lt = lr - 4;
    int local = b - tbase;
    int face = local >> (2 * lt);
    int rem  = local & ((1 << (2 * lt)) - 1);
    int ty0 = (rem >> lt) << 4;
    int tx0 = (rem & ((1 << lt) - 1)) << 4;
    int fbase = face << (2 * lr);

    for (int e = tid; e < 289; e += 256) {
        int ey = e / 17, ex = e - ey * 17;
        int gy = min(ty0 + ey, W - 1), gx = min(tx0 + ex, W - 1);
        int idx = 3 * (fbase + (gy << lr) + gx);
        L[e] = enc9e5(src[idx], src[idx + 1], src[idx + 2]);
    }
    __syncthreads();
    int qx = tid & 15, qy = tid >> 4;
    uint4 qv;
    qv.x = L[qy * 17 + qx];       qv.y = L[qy * 17 + qx + 1];
    qv.z = L[(qy + 1) * 17 + qx]; qv.w = L[(qy + 1) * 17 + qx + 1];
    dst[doff + fbase + ((ty0 + qy) << lr) + tx0 + qx] = qv;
}

// ---------------- main kernel: 2 pts/thread, lean pipelined state ----------------
// s_in float layout (512 pts): vd[0..1535] nm[1536..3071] kd[3072..4607]
//   ks[4608..6143] occ[6144..6655] = 26624 B -> 6 blocks/CU = 24 waves/CU.
// Outputs overwrite vd region (self-only access; no extra barrier).

struct Frac {
    float dtx, dty, ltx, lty, atx, aty, btx, bty, fmip;
};

// prep: reads vd/nm/rough from LDS, computes addresses, ISSUES the 4 texture
// loads. Live output: 9 fracs + 4 in-flight uint4.
__device__ __forceinline__ void prep_pt2(const float* s, int t, const uint4* __restrict__ q,
                                         Frac& p, uint4& qA, uint4& qB, uint4& ql, uint4& qd) {
    float vx = s[3 * t],        vy = s[3 * t + 1],        vz = s[3 * t + 2];
    float nx = s[1536 + 3 * t], ny = s[1536 + 3 * t + 1], nz = s[1536 + 3 * t + 2];
    float rough = s[4608 + 3 * t + 1];

    // reflect + normalize
    float vdotn = vx * nx + vy * ny + vz * nz;
    float rx = 2.f * vdotn * nx - vx;
    float ry = 2.f * vdotn * ny - vy;
    float rz = 2.f * vdotn * nz - vz;
    float rinv = __builtin_amdgcn_rsqf(fmaxf(rx * rx + ry * ry + rz * rz, 1e-20f));
    rx *= rinv; ry *= rinv; rz *= rinv;

    // diffuse address (lr=4)
    int dI;
    {
        int face; float u, v;
        cube_face_uv(nx, ny, nz, face, u, v);
        float fx = (u * 0.5f + 0.5f) * 16.f - 0.5f;
        float fy = (v * 0.5f + 0.5f) * 16.f - 0.5f;
        float x0f = floorf(fx), y0f = floorf(fy);
        p.dtx = fx - x0f; p.dty = fy - y0f;
        int x0 = min(max((int)x0f, 0), 15);
        int y0 = min(max((int)y0f, 0), 15);
        dI = DIF_OFF + (face << 8) + (y0 << 4) + x0;
    }

    // LUT address
    int lI;
    {
        float NdotV = fmaxf(vdotn, 1e-4f);
        float fx = NdotV * 256.f - 0.5f;
        float fy = rough * 256.f - 0.5f;
        float x0f = floorf(fx), y0f = floorf(fy);
        p.ltx = fx - x0f; p.lty = fy - y0f;
        int x0 = min(max((int)x0f, 0), 255);
        int y0 = min(max((int)y0f, 0), 255);
        lI = LUT_OFF + (y0 << 8) + x0;
    }

    // mip selection
    const float MINR = 0.08f, MAXR = 0.5f;
    float lo = (fminf(fmaxf(rough, MINR), MAXR) - MINR) * (4.0f / (MAXR - MINR));
    float hi = (fminf(fmaxf(rough, MAXR), 1.0f) - MAXR) * (1.0f / (1.0f - MAXR)) + 4.0f;
    float lvl = fminf(fmaxf((rough < MAXR) ? lo : hi, 0.f), 5.f);
    int l0 = min(max((int)floorf(lvl), 0), 5);
    int l1 = min(l0 + 1, 5);
    p.fmip = lvl - (float)l0;

    // spec A/B addresses
    int aI, bI;
    {
        int face; float u, v;
        cube_face_uv(rx, ry, rz, face, u, v);
        int lrA = 9 - l0, lrB = 9 - l1;
        float RA = (float)(1 << lrA);
        float fxA = (u * 0.5f + 0.5f) * RA - 0.5f;
        float fyA = (v * 0.5f + 0.5f) * RA - 0.5f;
        float fxB = (l0 == l1) ? fxA : (fxA + 0.5f) * 0.5f - 0.5f;
        float fyB = (l0 == l1) ? fyA : (fyA + 0.5f) * 0.5f - 0.5f;

        float x0fA = floorf(fxA), y0fA = floorf(fyA);
        p.atx = fxA - x0fA; p.aty = fyA - y0fA;
        int WA = 1 << lrA;
        int x0A = min(max((int)x0fA, 0), WA - 1);
        int y0A = min(max((int)y0fA, 0), WA - 1);
        aI = spec_off(l0) + (face << (2 * lrA)) + (y0A << lrA) + x0A;

        float x0fB = floorf(fxB), y0fB = floorf(fyB);
        p.btx = fxB - x0fB; p.bty = fyB - y0fB;
        int WB = 1 << lrB;
        int x0B = min(max((int)x0fB, 0), WB - 1);
        int y0B = min(max((int)y0fB, 0), WB - 1);
        bI = spec_off(l1) + (face << (2 * lrB)) + (y0B << lrB) + x0B;
    }

    // issue all 4 scattered loads; indices die here
    qA = q[aI];
    qB = q[bI];
    ql = q[lI];
    qd = q[dI];
}

// finish: re-reads kd/ks0/met/occ from LDS (hidden under vmcnt wait),
// writes result into s[3*t] (vd region reuse).
__device__ __forceinline__ void finish_pt2(float* s, int t, const Frac& p,
                                           uint4 qA, uint4 qB, uint4 ql, uint4 qd) {
    float kdx = s[3072 + 3 * t], kdy = s[3072 + 3 * t + 1], kdz = s[3072 + 3 * t + 2];
    float ks0 = s[4608 + 3 * t];
    float met = s[4608 + 3 * t + 2];
    float occ = s[6144 + t];

    float ar, ag, ab_, br, bg, bb;
    gather_q9(qA, p.atx, p.aty, ar, ag, ab_);
    gather_q9(qB, p.btx, p.bty, br, bg, bb);

    __half2 h00 = *reinterpret_cast<__half2*>(&ql.x);
    __half2 h01 = *reinterpret_cast<__half2*>(&ql.y);
    __half2 h10 = *reinterpret_cast<__half2*>(&ql.z);
    __half2 h11 = *reinterpret_cast<__half2*>(&ql.w);
    float2 c00 = __half22float2(h00), c01 = __half22float2(h01);
    float2 c10 = __half22float2(h10), c11 = __half22float2(h11);
    float lw00 = (1.f - p.ltx) * (1.f - p.lty);
    float lw01 = p.ltx * (1.f - p.lty);
    float lw10 = (1.f - p.ltx) * p.lty;
    float lw11 = p.ltx * p.lty;
    float fg0 = c00.x * lw00 + c01.x * lw01 + c10.x * lw10 + c11.x * lw11;
    float fg1 = c00.y * lw00 + c01.y * lw01 + c10.y * lw10 + c11.y * lw11;

    float dfr, dfg, dfb;
    gather_q9(qd, p.dtx, p.dty, dfr, dfg, dfb);
    dfr = fmaxf(dfr, 0.f); dfg = fmaxf(dfg, 0.f); dfb = fmaxf(dfb, 0.f);

    float spr = fmaxf(ar * (1.f - p.fmip) + br * p.fmip, 0.f);
    float spg = fmaxf(ag * (1.f - p.fmip) + bg * p.fmip, 0.f);
    float spb = fmaxf(ab_ * (1.f - p.fmip) + bb * p.fmip, 0.f);

    float m = met;
    float scx = (1.f - m) * 0.04f + kdx * m;
    float scy = (1.f - m) * 0.04f + kdy * m;
    float scz = (1.f - m) * 0.04f + kdz * m;
    float dcx = kdx * (1.f - m);
    float dcy = kdy * (1.f - m);
    float dcz = kdz * (1.f - m);

    float kds = 1.f - ks0;
    float om = 1.f - occ;
    float shx = dfr * dcx * kds + spr * (scx * fg0 + fg1) * om;
    float shy = dfg * dcy * kds + spg * (scy * fg0 + fg1) * om;
    float shz = dfb * dcz * kds + spb * (scz * fg0 + fg1) * om;

    s[3 * t + 0] = srgb1(fminf(fmaxf(shx, 0.f), 1.f));
    s[3 * t + 1] = srgb1(fminf(fmaxf(shy, 0.f), 1.f));
    s[3 * t + 2] = srgb1(fminf(fmaxf(shz, 0.f), 1.f));
}

__global__ __launch_bounds__(256, 6)
void envlight_p2(const float* __restrict__ view_dir,
                 const float* __restrict__ normal,
                 const float* __restrict__ kd,
                 const float* __restrict__ ks,
                 const float* __restrict__ reflect_occ,
                 const uint4* __restrict__ q,
                 float* __restrict__ out, int n)
{
    __shared__ float s_in[6656];
    int tid = threadIdx.x;
    int base = blockIdx.x << 9;
    int nblk = min(512, n - base);

    if (nblk == 512) {
        const float4* v4 = (const float4*)(view_dir + 3 * base);
        const float4* n4 = (const float4*)(normal + 3 * base);
        const float4* k4 = (const float4*)(kd + 3 * base);
        const float4* q4 = (const float4*)(ks + 3 * base);
        const float4* o4 = (const float4*)(reflect_occ + base);
        float4* dst4 = (float4*)s_in;
        #pragma unroll
        for (int k = 0; k < 7; ++k) {
            int j = tid + (k << 8);
            if (j < 1664) {
                const float4* src; int off;
                if (j < 384)       { src = v4; off = j; }
                else if (j < 768)  { src = n4; off = j - 384; }
                else if (j < 1152) { src = k4; off = j - 768; }
                else if (j < 1536) { src = q4; off = j - 1152; }
                else               { src = o4; off = j - 1536; }
                dst4[j] = src[off];
            }
        }
    } else {
        for (int j = tid; j < nblk * 3; j += 256) {
            s_in[j]        = view_dir[3 * base + j];
            s_in[1536 + j] = normal[3 * base + j];
            s_in[3072 + j] = kd[3 * base + j];
            s_in[4608 + j] = ks[3 * base + j];
        }
        for (int j = tid; j < nblk; j += 256)
            s_in[6144 + j] = reflect_occ[base + j];
    }
    __syncthreads();

    bool a0 = (tid < nblk);
    bool a1 = (tid + 256 < nblk);

    Frac f0, f1;
    uint4 qA0, qB0, ql0, qd0, qA1, qB1, ql1, qd1;

    if (a0) prep_pt2(s_in, tid,       q, f0, qA0, qB0, ql0, qd0);
    if (a1) prep_pt2(s_in, tid + 256, q, f1, qA1, qB1, ql1, qd1);
    if (a0) finish_pt2(s_in, tid,       f0, qA0, qB0, ql0, qd0);
    if (a1) finish_pt2(s_in, tid + 256, f1, qA1, qB1, ql1, qd1);

    __syncthreads();   // outputs staged in s_in[0..1535]

    if (nblk == 512) {
        float4* ot4 = (float4*)(out + 3 * base);
        #pragma unroll
        for (int k = 0; k < 2; ++k) {
            int j = tid + (k << 8);
            if (j < 384) ot4[j] = ((const float4*)s_in)[j];
        }
    } else {
        for (int j = tid; j < nblk * 3; j += 256)
            out[3 * base + j] = s_in[j];
    }
}

// ---------------- raw-float fallback (ws too small; shouldn't trigger) ----------------
__global__ __launch_bounds__(256)
void envlight_raw(const float* __restrict__ view_dir,
                  const float* __restrict__ normal,
                  const float* __restrict__ kd,
                  const float* __restrict__ ks,
                  const float* __restrict__ reflect_occ,
                  const float* __restrict__ diffuse_map,
                  const float* __restrict__ s0, const float* __restrict__ s1,
                  const float* __restrict__ s2, const float* __restrict__ s3,
                  const float* __restrict__ s4, const float* __restrict__ s5,
                  const float* __restrict__ fg_lut,
                  float* __restrict__ out, int n)
{
    int i = blockIdx.x * blockDim.x + threadIdx.x;
    if (i >= n) return;

    float vx = view_dir[3 * i], vy = view_dir[3 * i + 1], vz = view_dir[3 * i + 2];
    float nx = normal[3 * i],  ny = normal[3 * i + 1],  nz = normal[3 * i + 2];
    float kdx = kd[3 * i], kdy = kd[3 * i + 1], kdz = kd[3 * i + 2];
    float ks0 = ks[3 * i], rough = ks[3 * i + 1], metallic = ks[3 * i + 2];
    float occ = reflect_occ[i];

    float vdotn = vx * nx + vy * ny + vz * nz;
    float rx = 2.f * vdotn * nx - vx;
    float ry = 2.f * vdotn * ny - vy;
    float rz = 2.f * vdotn * nz - vz;
    float rinv = __builtin_amdgcn_rsqf(fmaxf(rx * rx + ry * ry + rz * rz, 1e-20f));
    rx *= rinv; ry *= rinv; rz *= rinv;

    const float* mips[6] = {s0, s1, s2, s3, s4, s5};

    const float MINR = 0.08f, MAXR = 0.5f;
    float lo = (fminf(fmaxf(rough, MINR), MAXR) - MINR) * (4.0f / (MAXR - MINR));
    float hi = (fminf(fmaxf(rough, MAXR), 1.0f) - MAXR) * (1.0f / (1.0f - MAXR)) + 4.0f;
    float lvl = fminf(fmaxf((rough < MAXR) ? lo : hi, 0.f), 5.f);
    int l0 = min(max((int)floorf(lvl), 0), 5);
    int l1 = min(l0 + 1, 5);
    float f = lvl - (float)l0;

    float acc[3][3];
    float dirs[3][3] = {{nx, ny, nz}, {rx, ry, rz}, {rx, ry, rz}};
    int lrs[3] = {4, 9 - l0, 9 - l1};
    const float* texs[3] = {diffuse_map, mips[l0], mips[l1]};
    for (int s = 0; s < 3; ++s) {
        int face; float u, v;
        cube_face_uv(dirs[s][0], dirs[s][1], dirs[s][2], face, u, v);
        int lr = lrs[s], W = 1 << lr;
        float fx = (u * 0.5f + 0.5f) * (float)W - 0.5f;
        float fy = (v * 0.5f + 0.5f) * (float)W - 0.5f;
        float x0f = floorf(fx), y0f = floorf(fy);
        float tx = fx - x0f, ty = fy - y0f;
        int x0 = min(max((int)x0f, 0), W - 1);
        int x1 = min(x0 + 1, W - 1);
        int y0 = min(max((int)y0f, 0), W - 1);
        int y1 = min(y0 + 1, W - 1);
        int base = face << (2 * lr);
        const float* t = texs[s];
        const float* p00 = t + 3 * (base + (y0 << lr) + x0);
        const float* p01 = t + 3 * (base + (y0 << lr) + x1);
        const float* p10 = t + 3 * (base + (y1 << lr) + x0);
        const float* p11 = t + 3 * (base + (y1 << lr) + x1);
        float w00 = (1.f - tx) * (1.f - ty), w01 = tx * (1.f - ty);
        float w10 = (1.f - tx) * ty, w11 = tx * ty;
        for (int c = 0; c < 3; ++c)
            acc[s][c] = p00[c] * w00 + p01[c] * w01 + p10[c] * w10 + p11[c] * w11;
    }

    float NdotV = fmaxf(vdotn, 1e-4f);
    float fx = NdotV * 256.f - 0.5f, fy = rough * 256.f - 0.5f;
    float x0f = floorf(fx), y0f = floorf(fy);
    float tx = fx - x0f, ty = fy - y0f;
    int x0 = min(max((int)x0f, 0), 255);
    int x1 = min(x0 + 1, 255);
    int y0 = min(max((int)y0f, 0), 255);
    int y1 = min(y0 + 1, 255);
    const float2* lut2 = (const float2*)fg_lut;
    float2 c00 = lut2[(y0 << 8) + x0], c01 = lut2[(y0 << 8) + x1];
    float2 c10 = lut2[(y1 << 8) + x0], c11 = lut2[(y1 << 8) + x1];
    float w00 = (1.f - tx) * (1.f - ty), w01 = tx * (1.f - ty);
    float w10 = (1.f - tx) * ty, w11 = tx * ty;
    float fg0 = c00.x * w00 + c01.x * w01 + c10.x * w10 + c11.x * w11;
    float fg1 = c00.y * w00 + c01.y * w01 + c10.y * w10 + c11.y * w11;

    float dfr = fmaxf(acc[0][0], 0.f), dfg = fmaxf(acc[0][1], 0.f), dfb = fmaxf(acc[0][2], 0.f);
    float spr = fmaxf(acc[1][0] * (1.f - f) + acc[2][0] * f, 0.f);
    float spg = fmaxf(acc[1][1] * (1.f - f) + acc[2][1] * f, 0.f);
    float spb = fmaxf(acc[1][2] * (1.f - f) + acc[2][2] * f, 0.f);

    float m = metallic;
    float scx = (1.f - m) * 0.04f + kdx * m;
    float scy = (1.f - m) * 0.04f + kdy * m;
    float scz = (1.f - m) * 0.04f + kdz * m;
    float kds = 1.f - ks0;
    float om = 1.f - occ;
    float shx = dfr * kdx * (1.f - m) * kds + spr * (scx * fg0 + fg1) * om;
    float shy = dfg * kdy * (1.f - m) * kds + spg * (scy * fg0 + fg1) * om;
    float shz = dfb * kdz * (1.f - m) * kds + spb * (scz * fg0 + fg1) * om;

    out[3 * i + 0] = srgb1(fminf(fmaxf(shx, 0.f), 1.f));
    out[3 * i + 1] = srgb1(fminf(fmaxf(shy, 0.f), 1.f));
    out[3 * i + 2] = srgb1(fminf(fmaxf(shz, 0.f), 1.f));
}

extern "C" void kernel_launch(void* const* d_in, const int* in_sizes, int n_in,
                              void* d_out, int out_size, void* d_ws, size_t ws_size,
                              hipStream_t stream) {
    const float* view_dir    = (const float*)d_in[0];
    const float* normal      = (const float*)d_in[1];
    const float* kd          = (const float*)d_in[2];
    const float* ks          = (const float*)d_in[3];
    const float* reflect_occ = (const float*)d_in[4];
    const float* diffuse_map = (const float*)d_in[5];
    const float* s0          = (const float*)d_in[6];
    const float* s1          = (const float*)d_in[7];
    const float* s2          = (const float*)d_in[8];
    const float* s3          = (const float*)d_in[9];
    const float* s4          = (const float*)d_in[10];
    const float* s5          = (const float*)d_in[11];
    const float* fg_lut      = (const float*)d_in[12];
    float* out = (float*)d_out;

    int n = in_sizes[0] / 3;
    const size_t NEED_Q = (size_t)ALL_QUADS * 16;   // ~34.6 MB

    if (ws_size >= NEED_Q) {
        uint4* q = (uint4*)d_ws;
        repack_tiled<<<N_TILES, 256, 0, stream>>>(
            s0, s1, s2, s3, s4, s5, diffuse_map, (const float2*)fg_lut, q);
        int grid = (n + 511) / 512;
        envlight_p2<<<grid, 256, 0, stream>>>(
            view_dir, normal, kd, ks, reflect_occ, q, out, n);
    } else {
        int grid = (n + 255) / 256;
        envlight_raw<<<grid, 256, 0, stream>>>(
            view_dir, normal, kd, ks, reflect_occ, diffuse_map,
            s0, s1, s2, s3, s4, s5, fg_lut, out, n);
    }
}

// Round 4
// 228.912 us; speedup vs baseline: 1.0902x; 1.0577x over previous
//
#include <hip/hip_runtime.h>
#include <hip/hip_fp16.h>
#include <math.h>

// EnvironmentLight IBL shade, R13.
// R12 post-mortem: 2-pt-in-registers still spilled (~50MB scratch writes).
// Register-ILP approach abandoned. R13 gets the same latency overlap from
// CHUNK PIPELINING through LDS (T3/T14 pattern), zero extra register cost:
//  - grid-stride loop, 2048 blocks x 4 chunks of 256 pts
//  - double-buffered LDS (2 x 13.3KB = 26.6KB -> 6 blocks/CU)
//  - staging via __builtin_amdgcn_global_load_lds width=16 (no staging regs,
//    no VALU round-trip); section boundaries all multiples of 64 lanes
//  - ONE barrier per chunk: barrier -> issue next-chunk gload_lds -> compute cur
//  - outputs stored direct to global (contiguous per lane), no out-staging
// Compute body = R10's proven 1-pt shading (32 VGPR), so no spill possible.

typedef unsigned int u32;

// ---------------- RGB9E5 ----------------
__device__ __forceinline__ u32 enc9e5(float r, float g, float b) {
    r = fminf(fmaxf(r, 0.f), 65408.f);
    g = fminf(fmaxf(g, 0.f), 65408.f);
    b = fminf(fmaxf(b, 0.f), 65408.f);
    float maxc = fmaxf(r, fmaxf(g, b));
    int e = ((__float_as_int(maxc) >> 23) & 0xff) - 127;
    int exp_p = max(e + 16, 0);
    float rd = __int_as_float((151 - exp_p) << 23);   // 2^(24-exp_p), exact
    int maxm = (int)(maxc * rd + 0.5f);
    if (maxm == 512) { exp_p += 1; rd *= 0.5f; }
    u32 rm = (u32)(r * rd + 0.5f);
    u32 gm = (u32)(g * rd + 0.5f);
    u32 bm = (u32)(b * rd + 0.5f);
    return rm | (gm << 9) | (bm << 18) | ((u32)exp_p << 27);
}

__device__ __forceinline__ void dec9e5_acc(u32 pk, float w, float& r, float& g, float& b) {
    float scale = __int_as_float((int)(((pk >> 27) & 31u) + 103u) << 23) * w;
    r += (float)(pk & 511u) * scale;
    g += (float)((pk >> 9) & 511u) * scale;
    b += (float)((pk >> 18) & 511u) * scale;
}

__device__ __forceinline__ void gather_q9(uint4 q, float tx, float ty,
                                          float& r, float& g, float& b) {
    float w00 = (1.f - tx) * (1.f - ty);
    float w01 = tx * (1.f - ty);
    float w10 = (1.f - tx) * ty;
    float w11 = tx * ty;
    r = 0.f; g = 0.f; b = 0.f;
    dec9e5_acc(q.x, w00, r, g, b);
    dec9e5_acc(q.y, w01, r, g, b);
    dec9e5_acc(q.z, w10, r, g, b);
    dec9e5_acc(q.w, w11, r, g, b);
}

__device__ __forceinline__ float srgb1(float x) {
    float p = 1.055f * __builtin_amdgcn_exp2f(
                  __builtin_amdgcn_logf(fmaxf(x, 0.0031308f)) * (1.0f / 2.4f)) - 0.055f;
    return (x <= 0.0031308f) ? (12.92f * x) : p;
}

__device__ __forceinline__ void cube_face_uv(float dx, float dy, float dz,
                                             int& face, float& u, float& v) {
    float ax = fabsf(dx), ay = fabsf(dy), az = fabsf(dz);
    bool is_x = (ax >= ay) && (ax >= az);
    bool is_y = (!is_x) && (ay >= az);
    face = is_x ? (dx > 0.f ? 0 : 1)
                : (is_y ? (dy > 0.f ? 2 : 3) : (dz > 0.f ? 4 : 5));
    float ma = fmaxf(is_x ? ax : (is_y ? ay : az), 1e-20f);
    float uu = is_x ? (dx > 0.f ? -dz : dz) : (is_y ? dx : (dz > 0.f ? dx : -dx));
    float vv = is_y ? (dy > 0.f ? dz : -dz) : -dy;
    float inv = __builtin_amdgcn_rcpf(ma);
    u = uu * inv;
    v = vv * inv;
}

// ---------------- layout constants ----------------
#define SPEC_TOTAL 2096640
#define DIF_OFF    SPEC_TOTAL
#define LUT_OFF    (SPEC_TOTAL + 1536)
#define ALL_QUADS  (SPEC_TOTAL + 1536 + 65536)
#define N_TILES    8452   // 8190 spec + 6 dif + 256 lut
#define MAIN_GRID  2048

// OFF(l) = 2^21 - (2^21 >> 2l): 0,1572864,1966080,2064384,2088960,2095104
__device__ __forceinline__ int spec_off(int l) {
    return (1 << 21) - ((1 << 21) >> (2 * l));
}

// async global->LDS, 16B per lane. LDS dest = wave-uniform base + lane*16
// (our j mapping is lane-linear within each 64-lane group; section boundaries
// are multiples of 64, so src pointer is wave-group-uniform). [guide §5, m97]
__device__ __forceinline__ void gld16(const float4* g, float4* l) {
    __builtin_amdgcn_global_load_lds(
        (const __attribute__((address_space(1))) void*)g,
        (__attribute__((address_space(3))) void*)l,
        16, 0, 0);
}

// ---------------- tiled repack (unchanged from R11, verified) ----------------
__global__ __launch_bounds__(256)
void repack_tiled(const float* __restrict__ s0, const float* __restrict__ s1,
                  const float* __restrict__ s2, const float* __restrict__ s3,
                  const float* __restrict__ s4, const float* __restrict__ s5,
                  const float* __restrict__ diffuse_map,
                  const float2* __restrict__ lut,
                  uint4* __restrict__ dst)
{
    __shared__ u32 L[289];
    int b = blockIdx.x;
    int tid = threadIdx.x;

    if (b >= 8196) {
        int t = b - 8196;
        int ty0 = (t >> 4) << 4;
        int tx0 = (t & 15) << 4;
        for (int e = tid; e < 289; e += 256) {
            int ey = e / 17, ex = e - ey * 17;
            int gy = min(ty0 + ey, 255), gx = min(tx0 + ex, 255);
            float2 c = lut[(gy << 8) + gx];
            __half2 h = __floats2half2_rn(c.x, c.y);
            L[e] = *reinterpret_cast<u32*>(&h);
        }
        __syncthreads();
        int qx = tid & 15, qy = tid >> 4;
        uint4 qv;
        qv.x = L[qy * 17 + qx];       qv.y = L[qy * 17 + qx + 1];
        qv.z = L[(qy + 1) * 17 + qx]; qv.w = L[(qy + 1) * 17 + qx + 1];
        dst[LUT_OFF + ((ty0 + qy) << 8) + tx0 + qx] = qv;
        return;
    }

    const float* src; int lr, tbase, doff;
    if      (b < 6144) { src = s0; lr = 9; tbase = 0;    doff = 0; }
    else if (b < 7680) { src = s1; lr = 8; tbase = 6144; doff = 1572864; }
    else if (b < 8064) { src = s2; lr = 7; tbase = 7680; doff = 1966080; }
    else if (b < 8160) { src = s3; lr = 6; tbase = 8064; doff = 2064384; }
    else if (b < 8184) { src = s4; lr = 5; tbase = 8160; doff = 2088960; }
    else if (b < 8190) { src = s5; lr = 4; tbase = 8184; doff = 2095104; }
    else               { src = diffuse_map; lr = 4; tbase = 8190; doff = DIF_OFF; }

    int W = 1 << lr;
    int lt = lr - 4;
    int local = b - tbase;
    int face = local >> (2 * lt);
    int rem  = local & ((1 << (2 * lt)) - 1);
    int ty0 = (rem >> lt) << 4;
    int tx0 = (rem & ((1 << lt) - 1)) << 4;
    int fbase = face << (2 * lr);

    for (int e = tid; e < 289; e += 256) {
        int ey = e / 17, ex = e - ey * 17;
        int gy = min(ty0 + ey, W - 1), gx = min(tx0 + ex, W - 1);
        int idx = 3 * (fbase + (gy << lr) + gx);
        L[e] = enc9e5(src[idx], src[idx + 1], src[idx + 2]);
    }
    __syncthreads();
    int qx = tid & 15, qy = tid >> 4;
    uint4 qv;
    qv.x = L[qy * 17 + qx];       qv.y = L[qy * 17 + qx + 1];
    qv.z = L[(qy + 1) * 17 + qx]; qv.w = L[(qy + 1) * 17 + qx + 1];
    dst[doff + fbase + ((ty0 + qy) << lr) + tx0 + qx] = qv;
}

// ---------------- staging: one 256-pt chunk -> one LDS buffer ----------------
// buffer float layout: vd[0..767] nm[768..1535] kd[1536..2303] ks[2304..3071]
//   oc[3072..3327]  = 3328 floats = 13312 B.
__device__ __forceinline__ void stage_chunk(float* sb, int tid,
    const float* __restrict__ vd, const float* __restrict__ nm,
    const float* __restrict__ kd, const float* __restrict__ ks,
    const float* __restrict__ oc, int base, int nblk)
{
    if (nblk == 256) {
        const float4* v4 = (const float4*)(vd + 3 * base);
        const float4* n4 = (const float4*)(nm + 3 * base);
        const float4* k4 = (const float4*)(kd + 3 * base);
        const float4* q4 = (const float4*)(ks + 3 * base);
        const float4* o4 = (const float4*)(oc + base);
        float4* d4 = (float4*)sb;
        #pragma unroll
        for (int kk = 0; kk < 4; ++kk) {
            int j = tid + (kk << 8);
            if (j < 832) {                       // wave-uniform (64 | boundaries)
                const float4* src; int off;
                if (j < 192)      { src = v4; off = j; }
                else if (j < 384) { src = n4; off = j - 192; }
                else if (j < 576) { src = k4; off = j - 384; }
                else if (j < 768) { src = q4; off = j - 576; }
                else              { src = o4; off = j - 768; }
                gld16(src + off, d4 + j);
            }
        }
    } else {
        for (int j = tid; j < nblk * 3; j += 256) {
            sb[j]        = vd[3 * base + j];
            sb[768 + j]  = nm[3 * base + j];
            sb[1536 + j] = kd[3 * base + j];
            sb[2304 + j] = ks[3 * base + j];
        }
        for (int j = tid; j < nblk; j += 256)
            sb[3072 + j] = oc[base + j];
    }
}

// ---------------- shade one point from a staged buffer (R10 body) -----------
__device__ __forceinline__ void shade_pt(const float* s, int tid,
                                         const uint4* __restrict__ q,
                                         float* __restrict__ outp)
{
    float vx = s[3 * tid], vy = s[3 * tid + 1], vz = s[3 * tid + 2];
    float nx = s[768 + 3 * tid], ny = s[768 + 3 * tid + 1], nz = s[768 + 3 * tid + 2];
    float kdx = s[1536 + 3 * tid], kdy = s[1536 + 3 * tid + 1], kdz = s[1536 + 3 * tid + 2];
    float ks0 = s[2304 + 3 * tid], rough = s[2304 + 3 * tid + 1], metallic = s[2304 + 3 * tid + 2];
    float occ = s[3072 + tid];

    // reflect + normalize
    float vdotn = vx * nx + vy * ny + vz * nz;
    float rx = 2.f * vdotn * nx - vx;
    float ry = 2.f * vdotn * ny - vy;
    float rz = 2.f * vdotn * nz - vz;
    float rinv = __builtin_amdgcn_rsqf(fmaxf(rx * rx + ry * ry + rz * rz, 1e-20f));
    rx *= rinv; ry *= rinv; rz *= rinv;

    // diffuse address (lr=4)
    float dtx, dty; int dIdx;
    {
        int face; float u, v;
        cube_face_uv(nx, ny, nz, face, u, v);
        float fx = (u * 0.5f + 0.5f) * 16.f - 0.5f;
        float fy = (v * 0.5f + 0.5f) * 16.f - 0.5f;
        float x0f = floorf(fx), y0f = floorf(fy);
        dtx = fx - x0f; dty = fy - y0f;
        int x0 = min(max((int)x0f, 0), 15);
        int y0 = min(max((int)y0f, 0), 15);
        dIdx = (face << 8) + (y0 << 4) + x0;
    }

    // LUT address
    float ltx, lty; int lutI;
    {
        float NdotV = fmaxf(vdotn, 1e-4f);
        float fx = NdotV * 256.f - 0.5f;
        float fy = rough * 256.f - 0.5f;
        float x0f = floorf(fx), y0f = floorf(fy);
        ltx = fx - x0f; lty = fy - y0f;
        int x0 = min(max((int)x0f, 0), 255);
        int y0 = min(max((int)y0f, 0), 255);
        lutI = (y0 << 8) + x0;
    }

    // mip selection
    const float MINR = 0.08f, MAXR = 0.5f;
    float lo = (fminf(fmaxf(rough, MINR), MAXR) - MINR) * (4.0f / (MAXR - MINR));
    float hi = (fminf(fmaxf(rough, MAXR), 1.0f) - MAXR) * (1.0f / (1.0f - MAXR)) + 4.0f;
    float lvl = fminf(fmaxf((rough < MAXR) ? lo : hi, 0.f), 5.f);
    int l0 = min(max((int)floorf(lvl), 0), 5);
    int l1 = min(l0 + 1, 5);
    float fmip = lvl - (float)l0;

    // spec A address; B derived (same face, half-res coords)
    float atx, aty, btx, bty; int aIdx, bIdx;
    {
        int face; float u, v;
        cube_face_uv(rx, ry, rz, face, u, v);
        int lrA = 9 - l0, lrB = 9 - l1;
        float RA = (float)(1 << lrA);
        float fxA = (u * 0.5f + 0.5f) * RA - 0.5f;
        float fyA = (v * 0.5f + 0.5f) * RA - 0.5f;
        float fxB = (l0 == l1) ? fxA : (fxA + 0.5f) * 0.5f - 0.5f;
        float fyB = (l0 == l1) ? fyA : (fyA + 0.5f) * 0.5f - 0.5f;

        float x0fA = floorf(fxA), y0fA = floorf(fyA);
        atx = fxA - x0fA; aty = fyA - y0fA;
        int WA = 1 << lrA;
        int x0A = min(max((int)x0fA, 0), WA - 1);
        int y0A = min(max((int)y0fA, 0), WA - 1);
        aIdx = spec_off(l0) + (face << (2 * lrA)) + (y0A << lrA) + x0A;

        float x0fB = floorf(fxB), y0fB = floorf(fyB);
        btx = fxB - x0fB; bty = fyB - y0fB;
        int WB = 1 << lrB;
        int x0B = min(max((int)x0fB, 0), WB - 1);
        int y0B = min(max((int)y0fB, 0), WB - 1);
        bIdx = spec_off(l1) + (face << (2 * lrB)) + (y0B << lrB) + x0B;
    }

    uint4 qA = q[aIdx];
    uint4 qB = q[bIdx];
    uint4 lq = (q + LUT_OFF)[lutI];
    uint4 dq = (q + DIF_OFF)[dIdx];

    float ar, ag, ab_, br, bg, bb;
    gather_q9(qA, atx, aty, ar, ag, ab_);
    gather_q9(qB, btx, bty, br, bg, bb);

    __half2 h00 = *reinterpret_cast<__half2*>(&lq.x);
    __half2 h01 = *reinterpret_cast<__half2*>(&lq.y);
    __half2 h10 = *reinterpret_cast<__half2*>(&lq.z);
    __half2 h11 = *reinterpret_cast<__half2*>(&lq.w);
    float2 c00 = __half22float2(h00), c01 = __half22float2(h01);
    float2 c10 = __half22float2(h10), c11 = __half22float2(h11);
    float lw00 = (1.f - ltx) * (1.f - lty);
    float lw01 = ltx * (1.f - lty);
    float lw10 = (1.f - ltx) * lty;
    float lw11 = ltx * lty;
    float fg0 = c00.x * lw00 + c01.x * lw01 + c10.x * lw10 + c11.x * lw11;
    float fg1 = c00.y * lw00 + c01.y * lw01 + c10.y * lw10 + c11.y * lw11;

    float dfr, dfg, dfb;
    gather_q9(dq, dtx, dty, dfr, dfg, dfb);
    dfr = fmaxf(dfr, 0.f); dfg = fmaxf(dfg, 0.f); dfb = fmaxf(dfb, 0.f);

    float spr = fmaxf(ar * (1.f - fmip) + br * fmip, 0.f);
    float spg = fmaxf(ag * (1.f - fmip) + bg * fmip, 0.f);
    float spb = fmaxf(ab_ * (1.f - fmip) + bb * fmip, 0.f);

    float m = metallic;
    float scx = (1.f - m) * 0.04f + kdx * m;
    float scy = (1.f - m) * 0.04f + kdy * m;
    float scz = (1.f - m) * 0.04f + kdz * m;
    float dcx = kdx * (1.f - m);
    float dcy = kdy * (1.f - m);
    float dcz = kdz * (1.f - m);

    float kds = 1.f - ks0;
    float om = 1.f - occ;
    float shx = dfr * dcx * kds + spr * (scx * fg0 + fg1) * om;
    float shy = dfg * dcy * kds + spg * (scy * fg0 + fg1) * om;
    float shz = dfb * dcz * kds + spb * (scz * fg0 + fg1) * om;

    outp[0] = srgb1(fminf(fmaxf(shx, 0.f), 1.f));
    outp[1] = srgb1(fminf(fmaxf(shy, 0.f), 1.f));
    outp[2] = srgb1(fminf(fmaxf(shz, 0.f), 1.f));
}

// ---------------- main kernel: chunk-pipelined, double-buffered LDS ---------
__global__ __launch_bounds__(256, 6)
void envlight_pipe(const float* __restrict__ view_dir,
                   const float* __restrict__ normal,
                   const float* __restrict__ kd,
                   const float* __restrict__ ks,
                   const float* __restrict__ reflect_occ,
                   const uint4* __restrict__ q,
                   float* __restrict__ out, int n)
{
    __shared__ float s_in[2][3328];
    int tid = threadIdx.x;
    int nchunks = (n + 255) >> 8;
    int c = blockIdx.x;
    if (c >= nchunks) return;

    // prologue: stage first chunk into buffer 0
    stage_chunk(s_in[0], tid, view_dir, normal, kd, ks, reflect_occ,
                c << 8, min(256, n - (c << 8)));

    int t = 0;
    for (; c < nchunks; c += gridDim.x, ++t) {
        int cur = t & 1;
        __syncthreads();   // drains vmcnt: buf[cur] staged & visible; buf[cur^1] free

        int cn = c + gridDim.x;
        if (cn < nchunks)
            stage_chunk(s_in[cur ^ 1], tid, view_dir, normal, kd, ks, reflect_occ,
                        cn << 8, min(256, n - (cn << 8)));

        int base = c << 8;
        int nblk = min(256, n - base);
        if (tid < nblk)
            shade_pt(s_in[cur], tid, q, out + 3 * (base + tid));
    }
}

// ---------------- raw-float fallback (ws too small; shouldn't trigger) ----------------
__global__ __launch_bounds__(256)
void envlight_raw(const float* __restrict__ view_dir,
                  const float* __restrict__ normal,
                  const float* __restrict__ kd,
                  const float* __restrict__ ks,
                  const float* __restrict__ reflect_occ,
                  const float* __restrict__ diffuse_map,
                  const float* __restrict__ s0, const float* __restrict__ s1,
                  const float* __restrict__ s2, const float* __restrict__ s3,
                  const float* __restrict__ s4, const float* __restrict__ s5,
                  const float* __restrict__ fg_lut,
                  float* __restrict__ out, int n)
{
    int i = blockIdx.x * blockDim.x + threadIdx.x;
    if (i >= n) return;

    float vx = view_dir[3 * i], vy = view_dir[3 * i + 1], vz = view_dir[3 * i + 2];
    float nx = normal[3 * i],  ny = normal[3 * i + 1],  nz = normal[3 * i + 2];
    float kdx = kd[3 * i], kdy = kd[3 * i + 1], kdz = kd[3 * i + 2];
    float ks0 = ks[3 * i], rough = ks[3 * i + 1], metallic = ks[3 * i + 2];
    float occ = reflect_occ[i];

    float vdotn = vx * nx + vy * ny + vz * nz;
    float rx = 2.f * vdotn * nx - vx;
    float ry = 2.f * vdotn * ny - vy;
    float rz = 2.f * vdotn * nz - vz;
    float rinv = __builtin_amdgcn_rsqf(fmaxf(rx * rx + ry * ry + rz * rz, 1e-20f));
    rx *= rinv; ry *= rinv; rz *= rinv;

    const float* mips[6] = {s0, s1, s2, s3, s4, s5};

    const float MINR = 0.08f, MAXR = 0.5f;
    float lo = (fminf(fmaxf(rough, MINR), MAXR) - MINR) * (4.0f / (MAXR - MINR));
    float hi = (fminf(fmaxf(rough, MAXR), 1.0f) - MAXR) * (1.0f / (1.0f - MAXR)) + 4.0f;
    float lvl = fminf(fmaxf((rough < MAXR) ? lo : hi, 0.f), 5.f);
    int l0 = min(max((int)floorf(lvl), 0), 5);
    int l1 = min(l0 + 1, 5);
    float f = lvl - (float)l0;

    float acc[3][3];
    float dirs[3][3] = {{nx, ny, nz}, {rx, ry, rz}, {rx, ry, rz}};
    int lrs[3] = {4, 9 - l0, 9 - l1};
    const float* texs[3] = {diffuse_map, mips[l0], mips[l1]};
    for (int s = 0; s < 3; ++s) {
        int face; float u, v;
        cube_face_uv(dirs[s][0], dirs[s][1], dirs[s][2], face, u, v);
        int lr = lrs[s], W = 1 << lr;
        float fx = (u * 0.5f + 0.5f) * (float)W - 0.5f;
        float fy = (v * 0.5f + 0.5f) * (float)W - 0.5f;
        float x0f = floorf(fx), y0f = floorf(fy);
        float tx = fx - x0f, ty = fy - y0f;
        int x0 = min(max((int)x0f, 0), W - 1);
        int x1 = min(x0 + 1, W - 1);
        int y0 = min(max((int)y0f, 0), W - 1);
        int y1 = min(y0 + 1, W - 1);
        int base = face << (2 * lr);
        const float* t = texs[s];
        const float* p00 = t + 3 * (base + (y0 << lr) + x0);
        const float* p01 = t + 3 * (base + (y0 << lr) + x1);
        const float* p10 = t + 3 * (base + (y1 << lr) + x0);
        const float* p11 = t + 3 * (base + (y1 << lr) + x1);
        float w00 = (1.f - tx) * (1.f - ty), w01 = tx * (1.f - ty);
        float w10 = (1.f - tx) * ty, w11 = tx * ty;
        for (int c = 0; c < 3; ++c)
            acc[s][c] = p00[c] * w00 + p01[c] * w01 + p10[c] * w10 + p11[c] * w11;
    }

    float NdotV = fmaxf(vdotn, 1e-4f);
    float fx = NdotV * 256.f - 0.5f, fy = rough * 256.f - 0.5f;
    float x0f = floorf(fx), y0f = floorf(fy);
    float tx = fx - x0f, ty = fy - y0f;
    int x0 = min(max((int)x0f, 0), 255);
    int x1 = min(x0 + 1, 255);
    int y0 = min(max((int)y0f, 0), 255);
    int y1 = min(y0 + 1, 255);
    const float2* lut2 = (const float2*)fg_lut;
    float2 c00 = lut2[(y0 << 8) + x0], c01 = lut2[(y0 << 8) + x1];
    float2 c10 = lut2[(y1 << 8) + x0], c11 = lut2[(y1 << 8) + x1];
    float w00 = (1.f - tx) * (1.f - ty), w01 = tx * (1.f - ty);
    float w10 = (1.f - tx) * ty, w11 = tx * ty;
    float fg0 = c00.x * w00 + c01.x * w01 + c10.x * w10 + c11.x * w11;
    float fg1 = c00.y * w00 + c01.y * w01 + c10.y * w10 + c11.y * w11;

    float dfr = fmaxf(acc[0][0], 0.f), dfg = fmaxf(acc[0][1], 0.f), dfb = fmaxf(acc[0][2], 0.f);
    float spr = fmaxf(acc[1][0] * (1.f - f) + acc[2][0] * f, 0.f);
    float spg = fmaxf(acc[1][1] * (1.f - f) + acc[2][1] * f, 0.f);
    float spb = fmaxf(acc[1][2] * (1.f - f) + acc[2][2] * f, 0.f);

    float m = metallic;
    float scx = (1.f - m) * 0.04f + kdx * m;
    float scy = (1.f - m) * 0.04f + kdy * m;
    float scz = (1.f - m) * 0.04f + kdz * m;
    float kds = 1.f - ks0;
    float om = 1.f - occ;
    float shx = dfr * kdx * (1.f - m) * kds + spr * (scx * fg0 + fg1) * om;
    float shy = dfg * kdy * (1.f - m) * kds + spg * (scy * fg0 + fg1) * om;
    float shz = dfb * kdz * (1.f - m) * kds + spb * (scz * fg0 + fg1) * om;

    out[3 * i + 0] = srgb1(fminf(fmaxf(shx, 0.f), 1.f));
    out[3 * i + 1] = srgb1(fminf(fmaxf(shy, 0.f), 1.f));
    out[3 * i + 2] = srgb1(fminf(fmaxf(shz, 0.f), 1.f));
}

extern "C" void kernel_launch(void* const* d_in, const int* in_sizes, int n_in,
                              void* d_out, int out_size, void* d_ws, size_t ws_size,
                              hipStream_t stream) {
    const float* view_dir    = (const float*)d_in[0];
    const float* normal      = (const float*)d_in[1];
    const float* kd          = (const float*)d_in[2];
    const float* ks          = (const float*)d_in[3];
    const float* reflect_occ = (const float*)d_in[4];
    const float* diffuse_map = (const float*)d_in[5];
    const float* s0          = (const float*)d_in[6];
    const float* s1          = (const float*)d_in[7];
    const float* s2          = (const float*)d_in[8];
    const float* s3          = (const float*)d_in[9];
    const float* s4          = (const float*)d_in[10];
    const float* s5          = (const float*)d_in[11];
    const float* fg_lut      = (const float*)d_in[12];
    float* out = (float*)d_out;

    int n = in_sizes[0] / 3;
    const size_t NEED_Q = (size_t)ALL_QUADS * 16;   // ~34.6 MB

    if (ws_size >= NEED_Q) {
        uint4* q = (uint4*)d_ws;
        repack_tiled<<<N_TILES, 256, 0, stream>>>(
            s0, s1, s2, s3, s4, s5, diffuse_map, (const float2*)fg_lut, q);
        int nchunks = (n + 255) >> 8;
        int grid = min(nchunks, MAIN_GRID);
        envlight_pipe<<<grid, 256, 0, stream>>>(
            view_dir, normal, kd, ks, reflect_occ, q, out, n);
    } else {
        int grid = (n + 255) / 256;
        envlight_raw<<<grid, 256, 0, stream>>>(
            view_dir, normal, kd, ks, reflect_occ, diffuse_map,
            s0, s1, s2, s3, s4, s5, fg_lut, out, n);
    }
}

// Round 6
// 227.089 us; speedup vs baseline: 1.0989x; 1.0080x over previous
//
#include <hip/hip_runtime.h>
#include <hip/hip_fp16.h>
#include <math.h>

// EnvironmentLight IBL shade, R14 (resubmit — R5 bench was a container-level
// infra failure; kernel never ran, no counters).
// R13 post-mortem: chunk pipelining raised per-wave efficiency (VALU/occ
// 41%->60%) but paid for it in occupancy (73%->50%) -> net loss. Kernel is
// scattered-load LATENCY bound; binding resource = resident waves.
// Issue-rate arithmetic: ~10 VMEM instr/pt = ~4us of issue -> LDS staging
// saves instructions we don't need to save while costing waves we do need.
// R14: ZERO LDS. Direct dwordx3 input loads (stride-12 uses full lines),
// launch_bounds(256,8) caps VGPR at 64 -> 32 waves/CU possible.
// Diagnostic: WRITE_SIZE must stay 24.6MB (rise = forced spill).

typedef unsigned int u32;

// ---------------- RGB9E5 ----------------
__device__ __forceinline__ u32 enc9e5(float r, float g, float b) {
    r = fminf(fmaxf(r, 0.f), 65408.f);
    g = fminf(fmaxf(g, 0.f), 65408.f);
    b = fminf(fmaxf(b, 0.f), 65408.f);
    float maxc = fmaxf(r, fmaxf(g, b));
    int e = ((__float_as_int(maxc) >> 23) & 0xff) - 127;
    int exp_p = max(e + 16, 0);
    float rd = __int_as_float((151 - exp_p) << 23);   // 2^(24-exp_p), exact
    int maxm = (int)(maxc * rd + 0.5f);
    if (maxm == 512) { exp_p += 1; rd *= 0.5f; }
    u32 rm = (u32)(r * rd + 0.5f);
    u32 gm = (u32)(g * rd + 0.5f);
    u32 bm = (u32)(b * rd + 0.5f);
    return rm | (gm << 9) | (bm << 18) | ((u32)exp_p << 27);
}

__device__ __forceinline__ void dec9e5_acc(u32 pk, float w, float& r, float& g, float& b) {
    float scale = __int_as_float((int)(((pk >> 27) & 31u) + 103u) << 23) * w;
    r += (float)(pk & 511u) * scale;
    g += (float)((pk >> 9) & 511u) * scale;
    b += (float)((pk >> 18) & 511u) * scale;
}

__device__ __forceinline__ void gather_q9(uint4 q, float tx, float ty,
                                          float& r, float& g, float& b) {
    float w00 = (1.f - tx) * (1.f - ty);
    float w01 = tx * (1.f - ty);
    float w10 = (1.f - tx) * ty;
    float w11 = tx * ty;
    r = 0.f; g = 0.f; b = 0.f;
    dec9e5_acc(q.x, w00, r, g, b);
    dec9e5_acc(q.y, w01, r, g, b);
    dec9e5_acc(q.z, w10, r, g, b);
    dec9e5_acc(q.w, w11, r, g, b);
}

__device__ __forceinline__ float srgb1(float x) {
    float p = 1.055f * __builtin_amdgcn_exp2f(
                  __builtin_amdgcn_logf(fmaxf(x, 0.0031308f)) * (1.0f / 2.4f)) - 0.055f;
    return (x <= 0.0031308f) ? (12.92f * x) : p;
}

__device__ __forceinline__ void cube_face_uv(float dx, float dy, float dz,
                                             int& face, float& u, float& v) {
    float ax = fabsf(dx), ay = fabsf(dy), az = fabsf(dz);
    bool is_x = (ax >= ay) && (ax >= az);
    bool is_y = (!is_x) && (ay >= az);
    face = is_x ? (dx > 0.f ? 0 : 1)
                : (is_y ? (dy > 0.f ? 2 : 3) : (dz > 0.f ? 4 : 5));
    float ma = fmaxf(is_x ? ax : (is_y ? ay : az), 1e-20f);
    float uu = is_x ? (dx > 0.f ? -dz : dz) : (is_y ? dx : (dz > 0.f ? dx : -dx));
    float vv = is_y ? (dy > 0.f ? dz : -dz) : -dy;
    float inv = __builtin_amdgcn_rcpf(ma);
    u = uu * inv;
    v = vv * inv;
}

// ---------------- layout constants ----------------
#define SPEC_TOTAL 2096640
#define DIF_OFF    SPEC_TOTAL
#define LUT_OFF    (SPEC_TOTAL + 1536)
#define ALL_QUADS  (SPEC_TOTAL + 1536 + 65536)
#define N_TILES    8452   // 8190 spec + 6 dif + 256 lut

// OFF(l) = 2^21 - (2^21 >> 2l): 0,1572864,1966080,2064384,2088960,2095104
__device__ __forceinline__ int spec_off(int l) {
    return (1 << 21) - ((1 << 21) >> (2 * l));
}

// ---------------- tiled repack (unchanged from R11, verified) ----------------
__global__ __launch_bounds__(256)
void repack_tiled(const float* __restrict__ s0, const float* __restrict__ s1,
                  const float* __restrict__ s2, const float* __restrict__ s3,
                  const float* __restrict__ s4, const float* __restrict__ s5,
                  const float* __restrict__ diffuse_map,
                  const float2* __restrict__ lut,
                  uint4* __restrict__ dst)
{
    __shared__ u32 L[289];
    int b = blockIdx.x;
    int tid = threadIdx.x;

    if (b >= 8196) {
        int t = b - 8196;
        int ty0 = (t >> 4) << 4;
        int tx0 = (t & 15) << 4;
        for (int e = tid; e < 289; e += 256) {
            int ey = e / 17, ex = e - ey * 17;
            int gy = min(ty0 + ey, 255), gx = min(tx0 + ex, 255);
            float2 c = lut[(gy << 8) + gx];
            __half2 h = __floats2half2_rn(c.x, c.y);
            L[e] = *reinterpret_cast<u32*>(&h);
        }
        __syncthreads();
        int qx = tid & 15, qy = tid >> 4;
        uint4 qv;
        qv.x = L[qy * 17 + qx];       qv.y = L[qy * 17 + qx + 1];
        qv.z = L[(qy + 1) * 17 + qx]; qv.w = L[(qy + 1) * 17 + qx + 1];
        dst[LUT_OFF + ((ty0 + qy) << 8) + tx0 + qx] = qv;
        return;
    }

    const float* src; int lr, tbase, doff;
    if      (b < 6144) { src = s0; lr = 9; tbase = 0;    doff = 0; }
    else if (b < 7680) { src = s1; lr = 8; tbase = 6144; doff = 1572864; }
    else if (b < 8064) { src = s2; lr = 7; tbase = 7680; doff = 1966080; }
    else if (b < 8160) { src = s3; lr = 6; tbase = 8064; doff = 2064384; }
    else if (b < 8184) { src = s4; lr = 5; tbase = 8160; doff = 2088960; }
    else if (b < 8190) { src = s5; lr = 4; tbase = 8184; doff = 2095104; }
    else               { src = diffuse_map; lr = 4; tbase = 8190; doff = DIF_OFF; }

    int W = 1 << lr;
    int lt = lr - 4;
    int local = b - tbase;
    int face = local >> (2 * lt);
    int rem  = local & ((1 << (2 * lt)) - 1);
    int ty0 = (rem >> lt) << 4;
    int tx0 = (rem & ((1 << lt) - 1)) << 4;
    int fbase = face << (2 * lr);

    for (int e = tid; e < 289; e += 256) {
        int ey = e / 17, ex = e - ey * 17;
        int gy = min(ty0 + ey, W - 1), gx = min(tx0 + ex, W - 1);
        int idx = 3 * (fbase + (gy << lr) + gx);
        L[e] = enc9e5(src[idx], src[idx + 1], src[idx + 2]);
    }
    __syncthreads();
    int qx = tid & 15, qy = tid >> 4;
    uint4 qv;
    qv.x = L[qy * 17 + qx];       qv.y = L[qy * 17 + qx + 1];
    qv.z = L[(qy + 1) * 17 + qx]; qv.w = L[(qy + 1) * 17 + qx + 1];
    dst[doff + fbase + ((ty0 + qy) << lr) + tx0 + qx] = qv;
}

// ---------------- main kernel: zero LDS, direct loads, max occupancy --------
__global__ __launch_bounds__(256, 8)
void envlight_direct(const float* __restrict__ view_dir,
                     const float* __restrict__ normal,
                     const float* __restrict__ kd_p,
                     const float* __restrict__ ks_p,
                     const float* __restrict__ reflect_occ,
                     const uint4* __restrict__ q,
                     float* __restrict__ out, int n)
{
    int i = blockIdx.x * blockDim.x + threadIdx.x;
    if (i >= n) return;

    const float3 v3 = ((const float3*)view_dir)[i];
    const float3 n3 = ((const float3*)normal)[i];
    const float3 k3 = ((const float3*)kd_p)[i];
    const float3 s3 = ((const float3*)ks_p)[i];
    float occ = reflect_occ[i];

    float vx = v3.x, vy = v3.y, vz = v3.z;
    float nx = n3.x, ny = n3.y, nz = n3.z;
    float kdx = k3.x, kdy = k3.y, kdz = k3.z;
    float ks0 = s3.x, rough = s3.y, metallic = s3.z;

    // reflect + normalize
    float vdotn = vx * nx + vy * ny + vz * nz;
    float rx = 2.f * vdotn * nx - vx;
    float ry = 2.f * vdotn * ny - vy;
    float rz = 2.f * vdotn * nz - vz;
    float rinv = __builtin_amdgcn_rsqf(fmaxf(rx * rx + ry * ry + rz * rz, 1e-20f));
    rx *= rinv; ry *= rinv; rz *= rinv;

    // diffuse address (lr=4)
    float dtx, dty; int dIdx;
    {
        int face; float u, v;
        cube_face_uv(nx, ny, nz, face, u, v);
        float fx = (u * 0.5f + 0.5f) * 16.f - 0.5f;
        float fy = (v * 0.5f + 0.5f) * 16.f - 0.5f;
        float x0f = floorf(fx), y0f = floorf(fy);
        dtx = fx - x0f; dty = fy - y0f;
        int x0 = min(max((int)x0f, 0), 15);
        int y0 = min(max((int)y0f, 0), 15);
        dIdx = (face << 8) + (y0 << 4) + x0;
    }

    // LUT address
    float ltx, lty; int lutI;
    {
        float NdotV = fmaxf(vdotn, 1e-4f);
        float fx = NdotV * 256.f - 0.5f;
        float fy = rough * 256.f - 0.5f;
        float x0f = floorf(fx), y0f = floorf(fy);
        ltx = fx - x0f; lty = fy - y0f;
        int x0 = min(max((int)x0f, 0), 255);
        int y0 = min(max((int)y0f, 0), 255);
        lutI = (y0 << 8) + x0;
    }

    // mip selection
    const float MINR = 0.08f, MAXR = 0.5f;
    float lo = (fminf(fmaxf(rough, MINR), MAXR) - MINR) * (4.0f / (MAXR - MINR));
    float hi = (fminf(fmaxf(rough, MAXR), 1.0f) - MAXR) * (1.0f / (1.0f - MAXR)) + 4.0f;
    float lvl = fminf(fmaxf((rough < MAXR) ? lo : hi, 0.f), 5.f);
    int l0 = min(max((int)floorf(lvl), 0), 5);
    int l1 = min(l0 + 1, 5);
    float fmip = lvl - (float)l0;

    // spec A address; B derived (same face, half-res coords)
    float atx, aty, btx, bty; int aIdx, bIdx;
    {
        int face; float u, v;
        cube_face_uv(rx, ry, rz, face, u, v);
        int lrA = 9 - l0, lrB = 9 - l1;
        float RA = (float)(1 << lrA);
        float fxA = (u * 0.5f + 0.5f) * RA - 0.5f;
        float fyA = (v * 0.5f + 0.5f) * RA - 0.5f;
        float fxB = (l0 == l1) ? fxA : (fxA + 0.5f) * 0.5f - 0.5f;
        float fyB = (l0 == l1) ? fyA : (fyA + 0.5f) * 0.5f - 0.5f;

        float x0fA = floorf(fxA), y0fA = floorf(fyA);
        atx = fxA - x0fA; aty = fyA - y0fA;
        int WA = 1 << lrA;
        int x0A = min(max((int)x0fA, 0), WA - 1);
        int y0A = min(max((int)y0fA, 0), WA - 1);
        aIdx = spec_off(l0) + (face << (2 * lrA)) + (y0A << lrA) + x0A;

        float x0fB = floorf(fxB), y0fB = floorf(fyB);
        btx = fxB - x0fB; bty = fyB - y0fB;
        int WB = 1 << lrB;
        int x0B = min(max((int)x0fB, 0), WB - 1);
        int y0B = min(max((int)y0fB, 0), WB - 1);
        bIdx = spec_off(l1) + (face << (2 * lrB)) + (y0B << lrB) + x0B;
    }

    uint4 qA = q[aIdx];
    uint4 qB = q[bIdx];
    uint4 lq = (q + LUT_OFF)[lutI];
    uint4 dq = (q + DIF_OFF)[dIdx];

    float ar, ag, ab_, br, bg, bb;
    gather_q9(qA, atx, aty, ar, ag, ab_);
    gather_q9(qB, btx, bty, br, bg, bb);

    __half2 h00 = *reinterpret_cast<__half2*>(&lq.x);
    __half2 h01 = *reinterpret_cast<__half2*>(&lq.y);
    __half2 h10 = *reinterpret_cast<__half2*>(&lq.z);
    __half2 h11 = *reinterpret_cast<__half2*>(&lq.w);
    float2 c00 = __half22float2(h00), c01 = __half22float2(h01);
    float2 c10 = __half22float2(h10), c11 = __half22float2(h11);
    float lw00 = (1.f - ltx) * (1.f - lty);
    float lw01 = ltx * (1.f - lty);
    float lw10 = (1.f - ltx) * lty;
    float lw11 = ltx * lty;
    float fg0 = c00.x * lw00 + c01.x * lw01 + c10.x * lw10 + c11.x * lw11;
    float fg1 = c00.y * lw00 + c01.y * lw01 + c10.y * lw10 + c11.y * lw11;

    float dfr, dfg, dfb;
    gather_q9(dq, dtx, dty, dfr, dfg, dfb);
    dfr = fmaxf(dfr, 0.f); dfg = fmaxf(dfg, 0.f); dfb = fmaxf(dfb, 0.f);

    float spr = fmaxf(ar * (1.f - fmip) + br * fmip, 0.f);
    float spg = fmaxf(ag * (1.f - fmip) + bg * fmip, 0.f);
    float spb = fmaxf(ab_ * (1.f - fmip) + bb * fmip, 0.f);

    float m = metallic;
    float scx = (1.f - m) * 0.04f + kdx * m;
    float scy = (1.f - m) * 0.04f + kdy * m;
    float scz = (1.f - m) * 0.04f + kdz * m;
    float dcx = kdx * (1.f - m);
    float dcy = kdy * (1.f - m);
    float dcz = kdz * (1.f - m);

    float kds = 1.f - ks0;
    float om = 1.f - occ;
    float shx = dfr * dcx * kds + spr * (scx * fg0 + fg1) * om;
    float shy = dfg * dcy * kds + spg * (scy * fg0 + fg1) * om;
    float shz = dfb * dcz * kds + spb * (scz * fg0 + fg1) * om;

    out[3 * i + 0] = srgb1(fminf(fmaxf(shx, 0.f), 1.f));
    out[3 * i + 1] = srgb1(fminf(fmaxf(shy, 0.f), 1.f));
    out[3 * i + 2] = srgb1(fminf(fmaxf(shz, 0.f), 1.f));
}

// ---------------- raw-float fallback (ws too small; shouldn't trigger) ----------------
__global__ __launch_bounds__(256)
void envlight_raw(const float* __restrict__ view_dir,
                  const float* __restrict__ normal,
                  const float* __restrict__ kd,
                  const float* __restrict__ ks,
                  const float* __restrict__ reflect_occ,
                  const float* __restrict__ diffuse_map,
                  const float* __restrict__ s0, const float* __restrict__ s1,
                  const float* __restrict__ s2, const float* __restrict__ s3,
                  const float* __restrict__ s4, const float* __restrict__ s5,
                  const float* __restrict__ fg_lut,
                  float* __restrict__ out, int n)
{
    int i = blockIdx.x * blockDim.x + threadIdx.x;
    if (i >= n) return;

    float vx = view_dir[3 * i], vy = view_dir[3 * i + 1], vz = view_dir[3 * i + 2];
    float nx = normal[3 * i],  ny = normal[3 * i + 1],  nz = normal[3 * i + 2];
    float kdx = kd[3 * i], kdy = kd[3 * i + 1], kdz = kd[3 * i + 2];
    float ks0 = ks[3 * i], rough = ks[3 * i + 1], metallic = ks[3 * i + 2];
    float occ = reflect_occ[i];

    float vdotn = vx * nx + vy * ny + vz * nz;
    float rx = 2.f * vdotn * nx - vx;
    float ry = 2.f * vdotn * ny - vy;
    float rz = 2.f * vdotn * nz - vz;
    float rinv = __builtin_amdgcn_rsqf(fmaxf(rx * rx + ry * ry + rz * rz, 1e-20f));
    rx *= rinv; ry *= rinv; rz *= rinv;

    const float* mips[6] = {s0, s1, s2, s3, s4, s5};

    const float MINR = 0.08f, MAXR = 0.5f;
    float lo = (fminf(fmaxf(rough, MINR), MAXR) - MINR) * (4.0f / (MAXR - MINR));
    float hi = (fminf(fmaxf(rough, MAXR), 1.0f) - MAXR) * (1.0f / (1.0f - MAXR)) + 4.0f;
    float lvl = fminf(fmaxf((rough < MAXR) ? lo : hi, 0.f), 5.f);
    int l0 = min(max((int)floorf(lvl), 0), 5);
    int l1 = min(l0 + 1, 5);
    float f = lvl - (float)l0;

    float acc[3][3];
    float dirs[3][3] = {{nx, ny, nz}, {rx, ry, rz}, {rx, ry, rz}};
    int lrs[3] = {4, 9 - l0, 9 - l1};
    const float* texs[3] = {diffuse_map, mips[l0], mips[l1]};
    for (int s = 0; s < 3; ++s) {
        int face; float u, v;
        cube_face_uv(dirs[s][0], dirs[s][1], dirs[s][2], face, u, v);
        int lr = lrs[s], W = 1 << lr;
        float fx = (u * 0.5f + 0.5f) * (float)W - 0.5f;
        float fy = (v * 0.5f + 0.5f) * (float)W - 0.5f;
        float x0f = floorf(fx), y0f = floorf(fy);
        float tx = fx - x0f, ty = fy - y0f;
        int x0 = min(max((int)x0f, 0), W - 1);
        int x1 = min(x0 + 1, W - 1);
        int y0 = min(max((int)y0f, 0), W - 1);
        int y1 = min(y0 + 1, W - 1);
        int base = face << (2 * lr);
        const float* t = texs[s];
        const float* p00 = t + 3 * (base + (y0 << lr) + x0);
        const float* p01 = t + 3 * (base + (y0 << lr) + x1);
        const float* p10 = t + 3 * (base + (y1 << lr) + x0);
        const float* p11 = t + 3 * (base + (y1 << lr) + x1);
        float w00 = (1.f - tx) * (1.f - ty), w01 = tx * (1.f - ty);
        float w10 = (1.f - tx) * ty, w11 = tx * ty;
        for (int c = 0; c < 3; ++c)
            acc[s][c] = p00[c] * w00 + p01[c] * w01 + p10[c] * w10 + p11[c] * w11;
    }

    float NdotV = fmaxf(vdotn, 1e-4f);
    float fx = NdotV * 256.f - 0.5f, fy = rough * 256.f - 0.5f;
    float x0f = floorf(fx), y0f = floorf(fy);
    float tx = fx - x0f, ty = fy - y0f;
    int x0 = min(max((int)x0f, 0), 255);
    int x1 = min(x0 + 1, 255);
    int y0 = min(max((int)y0f, 0), 255);
    int y1 = min(y0 + 1, 255);
    const float2* lut2 = (const float2*)fg_lut;
    float2 c00 = lut2[(y0 << 8) + x0], c01 = lut2[(y0 << 8) + x1];
    float2 c10 = lut2[(y1 << 8) + x0], c11 = lut2[(y1 << 8) + x1];
    float w00 = (1.f - tx) * (1.f - ty), w01 = tx * (1.f - ty);
    float w10 = (1.f - tx) * ty, w11 = tx * ty;
    float fg0 = c00.x * w00 + c01.x * w01 + c10.x * w10 + c11.x * w11;
    float fg1 = c00.y * w00 + c01.y * w01 + c10.y * w10 + c11.y * w11;

    float dfr = fmaxf(acc[0][0], 0.f), dfg = fmaxf(acc[0][1], 0.f), dfb = fmaxf(acc[0][2], 0.f);
    float spr = fmaxf(acc[1][0] * (1.f - f) + acc[2][0] * f, 0.f);
    float spg = fmaxf(acc[1][1] * (1.f - f) + acc[2][1] * f, 0.f);
    float spb = fmaxf(acc[1][2] * (1.f - f) + acc[2][2] * f, 0.f);

    float m = metallic;
    float scx = (1.f - m) * 0.04f + kdx * m;
    float scy = (1.f - m) * 0.04f + kdy * m;
    float scz = (1.f - m) * 0.04f + kdz * m;
    float kds = 1.f - ks0;
    float om = 1.f - occ;
    float shx = dfr * kdx * (1.f - m) * kds + spr * (scx * fg0 + fg1) * om;
    float shy = dfg * kdy * (1.f - m) * kds + spg * (scy * fg0 + fg1) * om;
    float shz = dfb * kdz * (1.f - m) * kds + spb * (scz * fg0 + fg1) * om;

    out[3 * i + 0] = srgb1(fminf(fmaxf(shx, 0.f), 1.f));
    out[3 * i + 1] = srgb1(fminf(fmaxf(shy, 0.f), 1.f));
    out[3 * i + 2] = srgb1(fminf(fmaxf(shz, 0.f), 1.f));
}

extern "C" void kernel_launch(void* const* d_in, const int* in_sizes, int n_in,
                              void* d_out, int out_size, void* d_ws, size_t ws_size,
                              hipStream_t stream) {
    const float* view_dir    = (const float*)d_in[0];
    const float* normal      = (const float*)d_in[1];
    const float* kd          = (const float*)d_in[2];
    const float* ks          = (const float*)d_in[3];
    const float* reflect_occ = (const float*)d_in[4];
    const float* diffuse_map = (const float*)d_in[5];
    const float* s0          = (const float*)d_in[6];
    const float* s1          = (const float*)d_in[7];
    const float* s2          = (const float*)d_in[8];
    const float* s3          = (const float*)d_in[9];
    const float* s4          = (const float*)d_in[10];
    const float* s5          = (const float*)d_in[11];
    const float* fg_lut      = (const float*)d_in[12];
    float* out = (float*)d_out;

    int n = in_sizes[0] / 3;
    int block = 256;
    int grid = (n + block - 1) / block;
    const size_t NEED_Q = (size_t)ALL_QUADS * 16;   // ~34.6 MB

    if (ws_size >= NEED_Q) {
        uint4* q = (uint4*)d_ws;
        repack_tiled<<<N_TILES, 256, 0, stream>>>(
            s0, s1, s2, s3, s4, s5, diffuse_map, (const float2*)fg_lut, q);
        envlight_direct<<<grid, block, 0, stream>>>(
            view_dir, normal, kd, ks, reflect_occ, q, out, n);
    } else {
        envlight_raw<<<grid, block, 0, stream>>>(
            view_dir, normal, kd, ks, reflect_occ, diffuse_map,
            s0, s1, s2, s3, s4, s5, fg_lut, out, n);
    }
}